// Round 2
// baseline (1175.224 us; speedup 1.0000x reference)
//
#include <hip/hip_runtime.h>

#define NTOK 98
#define DIMC 128

typedef __attribute__((ext_vector_type(8))) short s8v;
typedef __attribute__((ext_vector_type(4))) float f4v;

#define LOG2E 1.4426950408889634f
#define QSCALE (0.17677669529663687f * LOG2E)  // 32^-0.5 * log2(e), folded into Wq/bq

__device__ __forceinline__ ushort f2bf(float f) {
  union { float fv; unsigned u; } c; c.fv = f;
  unsigned r = c.u + 0x7fffu + ((c.u >> 16) & 1u);
  return (ushort)(r >> 16);
}
__device__ __forceinline__ unsigned pack2(float a, float b) {
  return (unsigned)f2bf(a) | ((unsigned)f2bf(b) << 16);
}

// bm[w][h][i][j] = (mask[w][i][j] + rpb[rel_idx[i][j]][h]) * log2e  (9.83 MB, L2/L3-resident)
// qkv weights -> bf16, q-rows pre-scaled by SCALE*log2e; proj weights -> bf16.
__global__ void setup_kernel(const float* __restrict__ rpb, const int* __restrict__ rel_idx,
                             const float* __restrict__ maskg,
                             const float* __restrict__ qkv_w, const float* __restrict__ qkv_b,
                             const float* __restrict__ proj_w,
                             float* __restrict__ bm, ushort* __restrict__ qkv_wb,
                             float* __restrict__ qkv_bs, ushort* __restrict__ proj_wb) {
  int tid = blockIdx.x * blockDim.x + threadIdx.x;
  int stride = gridDim.x * blockDim.x;
  const int NN = NTOK * NTOK;
  for (int idx = tid; idx < 64 * 4 * NN; idx += stride) {
    int wh = idx / NN;          // w*4 + h
    int ij = idx % NN;
    int w = wh >> 2, h = wh & 3;
    bm[idx] = (maskg[w * NN + ij] + rpb[rel_idx[ij] * 4 + h]) * LOG2E;
  }
  for (int idx = tid; idx < 384 * DIMC; idx += stride) {
    float s = (idx < DIMC * DIMC) ? QSCALE : 1.0f;
    qkv_wb[idx] = f2bf(qkv_w[idx] * s);
  }
  for (int idx = tid; idx < 384; idx += stride)
    qkv_bs[idx] = qkv_b[idx] * ((idx < DIMC) ? QSCALE : 1.0f);
  for (int idx = tid; idx < DIMC * DIMC; idx += stride) proj_wb[idx] = f2bf(proj_w[idx]);
}

// One block per window. 8 waves; waves (2h,2h+1) own head h.
// LDS (68608 B total -> 2 blocks/CU):
//   [0, 32768)   : x-stage [112][128] bf16 swizzled  ->  P [8 waves][16][128] bf16 swizzled
//   [32768, 68608): k [4][112][40] ushorts (80 B rows: conflict-free bank walk)
//                   -> ao [112][128] bf16 swizzled (alias, after attention)
__global__ __launch_bounds__(512, 4)
void fused_wattn(const float* __restrict__ x, const float* __restrict__ bm_g,
                 const float* __restrict__ qkv_bs,
                 const ushort* __restrict__ qkv_wb, const ushort* __restrict__ proj_wb,
                 const float* __restrict__ proj_b, float* __restrict__ out) {
  __shared__ ushort smem[34304];
  const int b = blockIdx.x;
  const int tid = threadIdx.x;
  const int wave = tid >> 6;
  const int lane = tid & 63;
  const int l16 = lane & 15;
  const int lg = lane >> 4;
  const int head = wave >> 1;
  const int hf = wave & 1;
  const int it0 = hf * 3;

  char* xc = reinterpret_cast<char*>(smem);             // x-stage, then P region
  ushort* k_lds = smem + 16384;                         // [4][112][40]
  char* Pc = reinterpret_cast<char*>(smem) + wave * 4096;
  char* aoc = reinterpret_cast<char*>(smem + 16384);    // ao alias over k

  // ---- stage x -> bf16 LDS (swizzled), zero pad rows 98..111 ----
  {
    const float4* x4 = reinterpret_cast<const float4*>(x + (size_t)b * NTOK * DIMC);
    for (int i = tid; i < 3136; i += 512) {
      float4 f = x4[i];
      uint2 u; u.x = pack2(f.x, f.y); u.y = pack2(f.z, f.w);
      int row = i >> 5;
      int off = (i * 8) ^ ((row & 7) << 4);
      *reinterpret_cast<uint2*>(xc + off) = u;
    }
    uint2 z{0u, 0u};
    for (int i = tid; i < 448; i += 512)
      *reinterpret_cast<uint2*>(xc + 25088 + i * 8) = z;
  }
  __syncthreads();

  auto ldx = [&](int mt, int kc) -> s8v {
    int row = mt * 16 + l16;
    int off = (row * 256 + kc * 64 + lg * 16) ^ ((row & 7) << 4);
    return *reinterpret_cast<const s8v*>(xc + off);
  };

  const f4v fzero = {0.f, 0.f, 0.f, 0.f};

  // ---- QKV: q (swapped MFMA -> in-register A-frags via shfl) ----
  s8v qfrag[4];
  {
    s8v wq[2][4];
    float bq[2][4];
#pragma unroll
    for (int oi = 0; oi < 2; ++oi) {
      int o = 2 * head + oi;
#pragma unroll
      for (int kc = 0; kc < 4; ++kc)
        wq[oi][kc] = *reinterpret_cast<const s8v*>(&qkv_wb[(o * 16 + l16) * DIMC + kc * 32 + lg * 8]);
#pragma unroll
      for (int r = 0; r < 4; ++r) bq[oi][r] = qkv_bs[o * 16 + lg * 4 + r];
    }
#pragma unroll
    for (int ii = 0; ii < 4; ++ii) {
      int it = it0 + ii;
      s8v xf[4];
#pragma unroll
      for (int kc = 0; kc < 4; ++kc) xf[kc] = ldx(it, kc);
      f4v qs0 = fzero, qs1 = fzero;
#pragma unroll
      for (int kc = 0; kc < 4; ++kc) {
        qs0 = __builtin_amdgcn_mfma_f32_16x16x32_bf16(wq[0][kc], xf[kc], qs0, 0, 0, 0);
        qs1 = __builtin_amdgcn_mfma_f32_16x16x32_bf16(wq[1][kc], xf[kc], qs1, 0, 0, 0);
      }
#pragma unroll
      for (int r = 0; r < 4; ++r) { qs0[r] += bq[0][r]; qs1[r] += bq[1][r]; }
      // lane (l16=token, lg) needs channels lg*8+jj; src lane l16+16*((lg&1)*2+(jj>>2)), reg jj&3
      float vals[8];
#pragma unroll
      for (int jj = 0; jj < 8; ++jj) {
        int srcLane = l16 + 16 * ((lg & 1) * 2 + (jj >> 2));
        float a = __shfl(qs0[jj & 3], srcLane);
        float c = __shfl(qs1[jj & 3], srcLane);
        vals[jj] = (lg & 2) ? c : a;
      }
      union { s8v v; unsigned u[4]; } t;
      t.u[0] = pack2(vals[0], vals[1]); t.u[1] = pack2(vals[2], vals[3]);
      t.u[2] = pack2(vals[4], vals[5]); t.u[3] = pack2(vals[6], vals[7]);
      qfrag[ii] = t.v;
    }
  }

  // ---- QKV: v (normal MFMA -> in-register B-frags via shfl over mt pairs) ----
  s8v vfrag[2][4];
  {
    s8v wv[2][4];
    float bv[2];
#pragma unroll
    for (int oi = 0; oi < 2; ++oi) {
      int o = 16 + 2 * head + oi;
#pragma unroll
      for (int kc = 0; kc < 4; ++kc)
        wv[oi][kc] = *reinterpret_cast<const s8v*>(&qkv_wb[(o * 16 + l16) * DIMC + kc * 32 + lg * 8]);
      bv[oi] = qkv_bs[256 + head * 32 + oi * 16 + l16];
    }
#pragma unroll
    for (int mtp = 0; mtp < 4; ++mtp) {
      f4v accA[2] = {fzero, fzero}, accB[2] = {fzero, fzero};
      {
        s8v xf[4];
#pragma unroll
        for (int kc = 0; kc < 4; ++kc) xf[kc] = ldx(2 * mtp, kc);
#pragma unroll
        for (int kc = 0; kc < 4; ++kc) {
          accA[0] = __builtin_amdgcn_mfma_f32_16x16x32_bf16(xf[kc], wv[0][kc], accA[0], 0, 0, 0);
          accA[1] = __builtin_amdgcn_mfma_f32_16x16x32_bf16(xf[kc], wv[1][kc], accA[1], 0, 0, 0);
        }
#pragma unroll
        for (int r = 0; r < 4; ++r) { accA[0][r] += bv[0]; accA[1][r] += bv[1]; }
      }
      if (mtp < 3) {  // mt=7 doesn't exist; tokens 112..127 stay 0 (P there is 0 anyway)
        s8v xf[4];
#pragma unroll
        for (int kc = 0; kc < 4; ++kc) xf[kc] = ldx(2 * mtp + 1, kc);
#pragma unroll
        for (int kc = 0; kc < 4; ++kc) {
          accB[0] = __builtin_amdgcn_mfma_f32_16x16x32_bf16(xf[kc], wv[0][kc], accB[0], 0, 0, 0);
          accB[1] = __builtin_amdgcn_mfma_f32_16x16x32_bf16(xf[kc], wv[1][kc], accB[1], 0, 0, 0);
        }
#pragma unroll
        for (int r = 0; r < 4; ++r) { accB[0][r] += bv[0]; accB[1][r] += bv[1]; }
      }
#pragma unroll
      for (int oi = 0; oi < 2; ++oi) {
        float vals[8];
#pragma unroll
        for (int jj = 0; jj < 8; ++jj) {
          int srcLane = l16 + 16 * ((lg & 1) * 2 + (jj >> 2));
          float a = __shfl(accA[oi][jj & 3], srcLane);
          float c = __shfl(accB[oi][jj & 3], srcLane);
          vals[jj] = (lg & 2) ? c : a;   // lg>>1 picks mt parity
        }
        union { s8v v; unsigned u[4]; } t;
        t.u[0] = pack2(vals[0], vals[1]); t.u[1] = pack2(vals[2], vals[3]);
        t.u[2] = pack2(vals[4], vals[5]); t.u[3] = pack2(vals[6], vals[7]);
        vfrag[oi][mtp] = t.v;
      }
    }
  }

  // ---- QKV: k -> LDS (wave w owns k-otile w; 80 B rows = conflict-free) ----
  {
    s8v wk[4];
#pragma unroll
    for (int kc = 0; kc < 4; ++kc)
      wk[kc] = *reinterpret_cast<const s8v*>(&qkv_wb[((8 + wave) * 16 + l16) * DIMC + kc * 32 + lg * 8]);
    float bk = qkv_bs[128 + wave * 16 + l16];
    ushort* kdst = k_lds + (wave >> 1) * (112 * 40) + (wave & 1) * 16 + l16;
#pragma unroll
    for (int mt = 0; mt < 7; ++mt) {
      f4v acc = fzero;
#pragma unroll
      for (int kc = 0; kc < 4; ++kc)
        acc = __builtin_amdgcn_mfma_f32_16x16x32_bf16(ldx(mt, kc), wk[kc], acc, 0, 0, 0);
#pragma unroll
      for (int r = 0; r < 4; ++r)
        kdst[(mt * 16 + lg * 4 + r) * 40] = f2bf(acc[r] + bk);
    }
  }
  __syncthreads();  // k ready; x region dead -> P may be written

  // zero this wave's P pad cols 112..127
  for (int idx = lane; idx < 256; idx += 64) {
    int rw = idx >> 4, cl = 112 + (idx & 15);
    int off = (rw * 256 + cl * 2) ^ ((rw & 7) << 4);
    *reinterpret_cast<ushort*>(Pc + off) = 0;
  }

  // ---- attention ----
  const float* bmp = bm_g + (size_t)((b & 63) * 4 + head) * (NTOK * NTOK);
  f4v oacc[4][2];
#pragma unroll
  for (int ii = 0; ii < 4; ++ii) {
    const int it = it0 + ii;
    f4v S[7];
#pragma unroll
    for (int jt = 0; jt < 7; ++jt) {
      s8v kf = *reinterpret_cast<const s8v*>(&k_lds[(head * 112 + jt * 16 + l16) * 40 + lg * 8]);
      S[jt] = __builtin_amdgcn_mfma_f32_16x16x32_bf16(qfrag[ii], kf, fzero, 0, 0, 0);
    }
    // + (bias+mask)*log2e ; invalid -> -1e30 (scale already folded into q)
#pragma unroll
    for (int r = 0; r < 4; ++r) {
      int i = it * 16 + lg * 4 + r;
      bool iv = (i < NTOK);
#pragma unroll
      for (int jt = 0; jt < 7; ++jt) {
        int j = jt * 16 + l16;
        S[jt][r] = (iv && j < NTOK) ? S[jt][r] + bmp[i * NTOK + j] : -1e30f;
      }
    }
    float srow[4];
#pragma unroll
    for (int r = 0; r < 4; ++r) {
      float m = S[0][r];
#pragma unroll
      for (int jt = 1; jt < 7; ++jt) m = fmaxf(m, S[jt][r]);
      m = fmaxf(m, __shfl_xor(m, 1));
      m = fmaxf(m, __shfl_xor(m, 2));
      m = fmaxf(m, __shfl_xor(m, 4));
      m = fmaxf(m, __shfl_xor(m, 8));
      float s = 0.f;
#pragma unroll
      for (int jt = 0; jt < 7; ++jt) {
        float p = exp2f(S[jt][r] - m);
        S[jt][r] = p;
        s += p;
      }
      s += __shfl_xor(s, 1);
      s += __shfl_xor(s, 2);
      s += __shfl_xor(s, 4);
      s += __shfl_xor(s, 8);
      srow[r] = s;
    }
    // P -> LDS bf16 (swizzled)
#pragma unroll
    for (int r = 0; r < 4; ++r) {
      int rw = lg * 4 + r;
#pragma unroll
      for (int jt = 0; jt < 7; ++jt) {
        int off = (rw * 256 + (jt * 16 + l16) * 2) ^ ((rw & 7) << 4);
        *reinterpret_cast<ushort*>(Pc + off) = f2bf(S[jt][r]);
      }
    }
    asm volatile("s_waitcnt lgkmcnt(0)" ::: "memory");
    f4v o0 = fzero, o1 = fzero;
#pragma unroll
    for (int kc = 0; kc < 4; ++kc) {
      int off = (l16 * 256 + kc * 64 + lg * 16) ^ ((l16 & 7) << 4);
      s8v pf = *reinterpret_cast<const s8v*>(Pc + off);
      o0 = __builtin_amdgcn_mfma_f32_16x16x32_bf16(pf, vfrag[0][kc], o0, 0, 0, 0);
      o1 = __builtin_amdgcn_mfma_f32_16x16x32_bf16(pf, vfrag[1][kc], o1, 0, 0, 0);
    }
#pragma unroll
    for (int r = 0; r < 4; ++r) {
      float inv = 1.0f / srow[r];
      o0[r] *= inv; o1[r] *= inv;
    }
    oacc[ii][0] = o0; oacc[ii][1] = o1;
  }
  __syncthreads();  // all k reads done -> ao may alias k region

  // ---- attn-out -> LDS bf16 (swizzled) ----
#pragma unroll
  for (int ii = 0; ii < 4; ++ii) {
    int it = it0 + ii;
#pragma unroll
    for (int r = 0; r < 4; ++r) {
      int n = it * 16 + lg * 4 + r;
      if (n < NTOK) {
        int c0 = head * 32 + l16;
        *reinterpret_cast<ushort*>(aoc + ((n * 256 + c0 * 2) ^ ((n & 7) << 4))) = f2bf(oacc[ii][0][r]);
        int c1 = c0 + 16;
        *reinterpret_cast<ushort*>(aoc + ((n * 256 + c1 * 2) ^ ((n & 7) << 4))) = f2bf(oacc[ii][1][r]);
      }
    }
  }
  __syncthreads();

  // ---- proj: wave w owns rows [16w,16w+16) so each 512 B out row is one wave's ----
  if (wave < 7) {
    float* outb = out + (size_t)b * NTOK * DIMC;
    const int row = wave * 16 + l16;
#pragma unroll
    for (int ot = 0; ot < 8; ++ot) {
      s8v pw[4];
#pragma unroll
      for (int kc = 0; kc < 4; ++kc)
        pw[kc] = *reinterpret_cast<const s8v*>(&proj_wb[(ot * 16 + l16) * DIMC + kc * 32 + lg * 8]);
      float pb = proj_b[ot * 16 + l16];
      f4v acc = fzero;
#pragma unroll
      for (int kc = 0; kc < 4; ++kc) {
        int off = (row * 256 + kc * 64 + lg * 16) ^ ((row & 7) << 4);
        s8v af = *reinterpret_cast<const s8v*>(aoc + off);
        acc = __builtin_amdgcn_mfma_f32_16x16x32_bf16(af, pw[kc], acc, 0, 0, 0);
      }
#pragma unroll
      for (int r = 0; r < 4; ++r) {
        int n = wave * 16 + lg * 4 + r;
        if (n < NTOK) outb[n * DIMC + ot * 16 + l16] = acc[r] + pb;
      }
    }
  }
}

extern "C" void kernel_launch(void* const* d_in, const int* in_sizes, int n_in,
                              void* d_out, int out_size, void* d_ws, size_t ws_size,
                              hipStream_t stream) {
  const float* x = (const float*)d_in[0];
  const float* mask = (const float*)d_in[1];
  const float* rpb = (const float*)d_in[2];
  const float* qkv_w = (const float*)d_in[3];
  const float* qkv_b = (const float*)d_in[4];
  const float* proj_w = (const float*)d_in[5];
  const float* proj_b = (const float*)d_in[6];
  const int* rel_idx = (const int*)d_in[7];

  char* ws = (char*)d_ws;
  float* bm = (float*)ws;                               // 64*4*98*98*4 = 9,834,496 B
  ushort* qkv_wb = (ushort*)(ws + 9834496);             // 384*128*2    =    98,304 B
  float* qkv_bs = (float*)(ws + 9834496 + 98304);       // 384*4        =     1,536 B
  ushort* proj_wb = (ushort*)(ws + 9834496 + 98304 + 1536);  // 128*128*2 =  32,768 B

  setup_kernel<<<dim3(1024), dim3(256), 0, stream>>>(rpb, rel_idx, mask, qkv_w, qkv_b,
                                                     proj_w, bm, qkv_wb, qkv_bs, proj_wb);
  fused_wattn<<<dim3(4096), dim3(512), 0, stream>>>(x, bm, qkv_bs, qkv_wb, proj_wb,
                                                    proj_b, (float*)d_out);
}

// Round 3
// 604.781 us; speedup vs baseline: 1.9432x; 1.9432x over previous
//
#include <hip/hip_runtime.h>

#define NTOK 98
#define DIMC 128

typedef __attribute__((ext_vector_type(8))) short s8v;
typedef __attribute__((ext_vector_type(4))) float f4v;

#define LOG2E 1.4426950408889634f
#define QSCALE (0.17677669529663687f * LOG2E)  // 32^-0.5 * log2(e), folded into Wq/bq

__device__ __forceinline__ ushort f2bf(float f) {
  union { float fv; unsigned u; } c; c.fv = f;
  unsigned r = c.u + 0x7fffu + ((c.u >> 16) & 1u);
  return (ushort)(r >> 16);
}
__device__ __forceinline__ unsigned pack2(float a, float b) {
  return (unsigned)f2bf(a) | ((unsigned)f2bf(b) << 16);
}

// bm[w][h][i][j] = (mask[w][i][j] + rpb[rel_idx[i][j]][h]) * log2e  (9.83 MB, L2/L3-resident)
// qkv weights -> bf16, q-rows pre-scaled by SCALE*log2e; proj weights -> bf16.
__global__ void setup_kernel(const float* __restrict__ rpb, const int* __restrict__ rel_idx,
                             const float* __restrict__ maskg,
                             const float* __restrict__ qkv_w, const float* __restrict__ qkv_b,
                             const float* __restrict__ proj_w,
                             float* __restrict__ bm, ushort* __restrict__ qkv_wb,
                             float* __restrict__ qkv_bs, ushort* __restrict__ proj_wb) {
  int tid = blockIdx.x * blockDim.x + threadIdx.x;
  int stride = gridDim.x * blockDim.x;
  const int NN = NTOK * NTOK;
  for (int idx = tid; idx < 64 * 4 * NN; idx += stride) {
    int wh = idx / NN;          // w*4 + h
    int ij = idx % NN;
    int w = wh >> 2, h = wh & 3;
    bm[idx] = (maskg[w * NN + ij] + rpb[rel_idx[ij] * 4 + h]) * LOG2E;
  }
  for (int idx = tid; idx < 384 * DIMC; idx += stride) {
    float s = (idx < DIMC * DIMC) ? QSCALE : 1.0f;
    qkv_wb[idx] = f2bf(qkv_w[idx] * s);
  }
  for (int idx = tid; idx < 384; idx += stride)
    qkv_bs[idx] = qkv_b[idx] * ((idx < DIMC) ? QSCALE : 1.0f);
  for (int idx = tid; idx < DIMC * DIMC; idx += stride) proj_wb[idx] = f2bf(proj_w[idx]);
}

// One block per window. 8 waves; waves (2h,2h+1) own head h.
// LDS (68608 B total; with <=128 VGPR -> 2 blocks/CU):
//   [0, 32768)    : x-stage [112][128] bf16 swizzled -> P [8 waves][16][128] bf16 swizzled
//   [32768, 68608): k [4][112][40] ushorts (80 B rows: conflict-free bank walk)
//                   -> ao [112][128] bf16 swizzled (alias, after attention)
// NOTE: second launch_bounds arg empirically = min BLOCKS/CU for 512-thread blocks
// (r1: (512,2)->VGPR 128; r2: (512,4)->VGPR 64 + massive spill). Keep 2.
__global__ __launch_bounds__(512, 2)
void fused_wattn(const float* __restrict__ x, const float* __restrict__ bm_g,
                 const float* __restrict__ qkv_bs,
                 const ushort* __restrict__ qkv_wb, const ushort* __restrict__ proj_wb,
                 const float* __restrict__ proj_b, float* __restrict__ out) {
  __shared__ ushort smem[34304];
  const int b = blockIdx.x;
  const int tid = threadIdx.x;
  const int wave = tid >> 6;
  const int lane = tid & 63;
  const int l16 = lane & 15;
  const int lg = lane >> 4;
  const int head = wave >> 1;
  const int hf = wave & 1;
  const int it0 = hf * 3;

  char* xc = reinterpret_cast<char*>(smem);             // x-stage, then P region
  ushort* k_lds = smem + 16384;                         // [4][112][40]
  char* Pc = reinterpret_cast<char*>(smem) + wave * 4096;
  char* aoc = reinterpret_cast<char*>(smem + 16384);    // ao alias over k

  // ---- stage x -> bf16 LDS (swizzled), zero pad rows 98..111 ----
  {
    const float4* x4 = reinterpret_cast<const float4*>(x + (size_t)b * NTOK * DIMC);
    for (int i = tid; i < 3136; i += 512) {
      float4 f = x4[i];
      uint2 u; u.x = pack2(f.x, f.y); u.y = pack2(f.z, f.w);
      int row = i >> 5;
      int off = (i * 8) ^ ((row & 7) << 4);
      *reinterpret_cast<uint2*>(xc + off) = u;
    }
    uint2 z{0u, 0u};
    for (int i = tid; i < 448; i += 512)
      *reinterpret_cast<uint2*>(xc + 25088 + i * 8) = z;
  }
  __syncthreads();

  auto ldx = [&](int mt, int kc) -> s8v {
    int row = mt * 16 + l16;
    int off = (row * 256 + kc * 64 + lg * 16) ^ ((row & 7) << 4);
    return *reinterpret_cast<const s8v*>(xc + off);
  };

  const f4v fzero = {0.f, 0.f, 0.f, 0.f};

  // ---- QKV: q (swapped MFMA -> in-register A-frags via shfl) ----
  s8v qfrag[4];
  {
    s8v wq[2][4];
    float bq[2][4];
#pragma unroll
    for (int oi = 0; oi < 2; ++oi) {
      int o = 2 * head + oi;
#pragma unroll
      for (int kc = 0; kc < 4; ++kc)
        wq[oi][kc] = *reinterpret_cast<const s8v*>(&qkv_wb[(o * 16 + l16) * DIMC + kc * 32 + lg * 8]);
#pragma unroll
      for (int r = 0; r < 4; ++r) bq[oi][r] = qkv_bs[o * 16 + lg * 4 + r];
    }
#pragma unroll
    for (int ii = 0; ii < 4; ++ii) {
      int it = it0 + ii;
      s8v xf[4];
#pragma unroll
      for (int kc = 0; kc < 4; ++kc) xf[kc] = ldx(it, kc);
      f4v qs0 = fzero, qs1 = fzero;
#pragma unroll
      for (int kc = 0; kc < 4; ++kc) {
        qs0 = __builtin_amdgcn_mfma_f32_16x16x32_bf16(wq[0][kc], xf[kc], qs0, 0, 0, 0);
        qs1 = __builtin_amdgcn_mfma_f32_16x16x32_bf16(wq[1][kc], xf[kc], qs1, 0, 0, 0);
      }
#pragma unroll
      for (int r = 0; r < 4; ++r) { qs0[r] += bq[0][r]; qs1[r] += bq[1][r]; }
      // lane (l16=token, lg) needs channels lg*8+jj; src lane l16+16*((lg&1)*2+(jj>>2)), reg jj&3
      float vals[8];
#pragma unroll
      for (int jj = 0; jj < 8; ++jj) {
        int srcLane = l16 + 16 * ((lg & 1) * 2 + (jj >> 2));
        float a = __shfl(qs0[jj & 3], srcLane);
        float c = __shfl(qs1[jj & 3], srcLane);
        vals[jj] = (lg & 2) ? c : a;
      }
      union { s8v v; unsigned u[4]; } t;
      t.u[0] = pack2(vals[0], vals[1]); t.u[1] = pack2(vals[2], vals[3]);
      t.u[2] = pack2(vals[4], vals[5]); t.u[3] = pack2(vals[6], vals[7]);
      qfrag[ii] = t.v;
    }
  }

  // ---- QKV: v (normal MFMA -> in-register B-frags via shfl over mt pairs) ----
  s8v vfrag[2][4];
  {
    s8v wv[2][4];
    float bv[2];
#pragma unroll
    for (int oi = 0; oi < 2; ++oi) {
      int o = 16 + 2 * head + oi;
#pragma unroll
      for (int kc = 0; kc < 4; ++kc)
        wv[oi][kc] = *reinterpret_cast<const s8v*>(&qkv_wb[(o * 16 + l16) * DIMC + kc * 32 + lg * 8]);
      bv[oi] = qkv_bs[256 + head * 32 + oi * 16 + l16];
    }
#pragma unroll
    for (int mtp = 0; mtp < 4; ++mtp) {
      f4v accA[2] = {fzero, fzero}, accB[2] = {fzero, fzero};
      {
        s8v xf[4];
#pragma unroll
        for (int kc = 0; kc < 4; ++kc) xf[kc] = ldx(2 * mtp, kc);
#pragma unroll
        for (int kc = 0; kc < 4; ++kc) {
          accA[0] = __builtin_amdgcn_mfma_f32_16x16x32_bf16(xf[kc], wv[0][kc], accA[0], 0, 0, 0);
          accA[1] = __builtin_amdgcn_mfma_f32_16x16x32_bf16(xf[kc], wv[1][kc], accA[1], 0, 0, 0);
        }
#pragma unroll
        for (int r = 0; r < 4; ++r) { accA[0][r] += bv[0]; accA[1][r] += bv[1]; }
      }
      if (mtp < 3) {  // mt=7 doesn't exist; tokens 112..127 stay 0 (P there is 0 anyway)
        s8v xf[4];
#pragma unroll
        for (int kc = 0; kc < 4; ++kc) xf[kc] = ldx(2 * mtp + 1, kc);
#pragma unroll
        for (int kc = 0; kc < 4; ++kc) {
          accB[0] = __builtin_amdgcn_mfma_f32_16x16x32_bf16(xf[kc], wv[0][kc], accB[0], 0, 0, 0);
          accB[1] = __builtin_amdgcn_mfma_f32_16x16x32_bf16(xf[kc], wv[1][kc], accB[1], 0, 0, 0);
        }
#pragma unroll
        for (int r = 0; r < 4; ++r) { accB[0][r] += bv[0]; accB[1][r] += bv[1]; }
      }
#pragma unroll
      for (int oi = 0; oi < 2; ++oi) {
        float vals[8];
#pragma unroll
        for (int jj = 0; jj < 8; ++jj) {
          int srcLane = l16 + 16 * ((lg & 1) * 2 + (jj >> 2));
          float a = __shfl(accA[oi][jj & 3], srcLane);
          float c = __shfl(accB[oi][jj & 3], srcLane);
          vals[jj] = (lg & 2) ? c : a;   // lg>>1 picks mt parity
        }
        union { s8v v; unsigned u[4]; } t;
        t.u[0] = pack2(vals[0], vals[1]); t.u[1] = pack2(vals[2], vals[3]);
        t.u[2] = pack2(vals[4], vals[5]); t.u[3] = pack2(vals[6], vals[7]);
        vfrag[oi][mtp] = t.v;
      }
    }
  }

  // ---- QKV: k -> LDS (wave w owns k-otile w; 80 B rows = conflict-free) ----
  {
    s8v wk[4];
#pragma unroll
    for (int kc = 0; kc < 4; ++kc)
      wk[kc] = *reinterpret_cast<const s8v*>(&qkv_wb[((8 + wave) * 16 + l16) * DIMC + kc * 32 + lg * 8]);
    float bk = qkv_bs[128 + wave * 16 + l16];
    ushort* kdst = k_lds + (wave >> 1) * (112 * 40) + (wave & 1) * 16 + l16;
#pragma unroll
    for (int mt = 0; mt < 7; ++mt) {
      f4v acc = fzero;
#pragma unroll
      for (int kc = 0; kc < 4; ++kc)
        acc = __builtin_amdgcn_mfma_f32_16x16x32_bf16(ldx(mt, kc), wk[kc], acc, 0, 0, 0);
#pragma unroll
      for (int r = 0; r < 4; ++r)
        kdst[(mt * 16 + lg * 4 + r) * 40] = f2bf(acc[r] + bk);
    }
  }
  __syncthreads();  // k ready; x region dead -> P may be written

  // zero this wave's P pad cols 112..127
  for (int idx = lane; idx < 256; idx += 64) {
    int rw = idx >> 4, cl = 112 + (idx & 15);
    int off = (rw * 256 + cl * 2) ^ ((rw & 7) << 4);
    *reinterpret_cast<ushort*>(Pc + off) = 0;
  }

  // ---- attention ----
  const float* bmp = bm_g + (size_t)((b & 63) * 4 + head) * (NTOK * NTOK);
  f4v oacc[4][2];
#pragma unroll
  for (int ii = 0; ii < 4; ++ii) {
    const int it = it0 + ii;
    f4v S[7];
#pragma unroll
    for (int jt = 0; jt < 7; ++jt) {
      s8v kf = *reinterpret_cast<const s8v*>(&k_lds[(head * 112 + jt * 16 + l16) * 40 + lg * 8]);
      S[jt] = __builtin_amdgcn_mfma_f32_16x16x32_bf16(qfrag[ii], kf, fzero, 0, 0, 0);
    }
    // + (bias+mask)*log2e ; invalid -> -1e30 (scale already folded into q)
#pragma unroll
    for (int r = 0; r < 4; ++r) {
      int i = it * 16 + lg * 4 + r;
      bool iv = (i < NTOK);
#pragma unroll
      for (int jt = 0; jt < 7; ++jt) {
        int j = jt * 16 + l16;
        S[jt][r] = (iv && j < NTOK) ? S[jt][r] + bmp[i * NTOK + j] : -1e30f;
      }
    }
    float srow[4];
#pragma unroll
    for (int r = 0; r < 4; ++r) {
      float m = S[0][r];
#pragma unroll
      for (int jt = 1; jt < 7; ++jt) m = fmaxf(m, S[jt][r]);
      m = fmaxf(m, __shfl_xor(m, 1));
      m = fmaxf(m, __shfl_xor(m, 2));
      m = fmaxf(m, __shfl_xor(m, 4));
      m = fmaxf(m, __shfl_xor(m, 8));
      float s = 0.f;
#pragma unroll
      for (int jt = 0; jt < 7; ++jt) {
        float p = exp2f(S[jt][r] - m);
        S[jt][r] = p;
        s += p;
      }
      s += __shfl_xor(s, 1);
      s += __shfl_xor(s, 2);
      s += __shfl_xor(s, 4);
      s += __shfl_xor(s, 8);
      srow[r] = s;
    }
    // P -> LDS bf16 (swizzled)
#pragma unroll
    for (int r = 0; r < 4; ++r) {
      int rw = lg * 4 + r;
#pragma unroll
      for (int jt = 0; jt < 7; ++jt) {
        int off = (rw * 256 + (jt * 16 + l16) * 2) ^ ((rw & 7) << 4);
        *reinterpret_cast<ushort*>(Pc + off) = f2bf(S[jt][r]);
      }
    }
    asm volatile("s_waitcnt lgkmcnt(0)" ::: "memory");
    f4v o0 = fzero, o1 = fzero;
#pragma unroll
    for (int kc = 0; kc < 4; ++kc) {
      int off = (l16 * 256 + kc * 64 + lg * 16) ^ ((l16 & 7) << 4);
      s8v pf = *reinterpret_cast<const s8v*>(Pc + off);
      o0 = __builtin_amdgcn_mfma_f32_16x16x32_bf16(pf, vfrag[0][kc], o0, 0, 0, 0);
      o1 = __builtin_amdgcn_mfma_f32_16x16x32_bf16(pf, vfrag[1][kc], o1, 0, 0, 0);
    }
#pragma unroll
    for (int r = 0; r < 4; ++r) {
      float inv = 1.0f / srow[r];
      o0[r] *= inv; o1[r] *= inv;
    }
    oacc[ii][0] = o0; oacc[ii][1] = o1;
  }
  __syncthreads();  // all k reads done -> ao may alias k region

  // ---- attn-out -> LDS bf16 (swizzled) ----
#pragma unroll
  for (int ii = 0; ii < 4; ++ii) {
    int it = it0 + ii;
#pragma unroll
    for (int r = 0; r < 4; ++r) {
      int n = it * 16 + lg * 4 + r;
      if (n < NTOK) {
        int c0 = head * 32 + l16;
        *reinterpret_cast<ushort*>(aoc + ((n * 256 + c0 * 2) ^ ((n & 7) << 4))) = f2bf(oacc[ii][0][r]);
        int c1 = c0 + 16;
        *reinterpret_cast<ushort*>(aoc + ((n * 256 + c1 * 2) ^ ((n & 7) << 4))) = f2bf(oacc[ii][1][r]);
      }
    }
  }
  __syncthreads();

  // ---- proj: wave w owns rows [16w,16w+16) so each 512 B out row is one wave's ----
  if (wave < 7) {
    float* outb = out + (size_t)b * NTOK * DIMC;
    const int row = wave * 16 + l16;
#pragma unroll
    for (int ot = 0; ot < 8; ++ot) {
      s8v pw[4];
#pragma unroll
      for (int kc = 0; kc < 4; ++kc)
        pw[kc] = *reinterpret_cast<const s8v*>(&proj_wb[(ot * 16 + l16) * DIMC + kc * 32 + lg * 8]);
      float pb = proj_b[ot * 16 + l16];
      f4v acc = fzero;
#pragma unroll
      for (int kc = 0; kc < 4; ++kc) {
        int off = (row * 256 + kc * 64 + lg * 16) ^ ((row & 7) << 4);
        s8v af = *reinterpret_cast<const s8v*>(aoc + off);
        acc = __builtin_amdgcn_mfma_f32_16x16x32_bf16(af, pw[kc], acc, 0, 0, 0);
      }
#pragma unroll
      for (int r = 0; r < 4; ++r) {
        int n = wave * 16 + lg * 4 + r;
        if (n < NTOK) outb[n * DIMC + ot * 16 + l16] = acc[r] + pb;
      }
    }
  }
}

extern "C" void kernel_launch(void* const* d_in, const int* in_sizes, int n_in,
                              void* d_out, int out_size, void* d_ws, size_t ws_size,
                              hipStream_t stream) {
  const float* x = (const float*)d_in[0];
  const float* mask = (const float*)d_in[1];
  const float* rpb = (const float*)d_in[2];
  const float* qkv_w = (const float*)d_in[3];
  const float* qkv_b = (const float*)d_in[4];
  const float* proj_w = (const float*)d_in[5];
  const float* proj_b = (const float*)d_in[6];
  const int* rel_idx = (const int*)d_in[7];

  char* ws = (char*)d_ws;
  float* bm = (float*)ws;                               // 64*4*98*98*4 = 9,834,496 B
  ushort* qkv_wb = (ushort*)(ws + 9834496);             // 384*128*2    =    98,304 B
  float* qkv_bs = (float*)(ws + 9834496 + 98304);       // 384*4        =     1,536 B
  ushort* proj_wb = (ushort*)(ws + 9834496 + 98304 + 1536);  // 128*128*2 =  32,768 B

  setup_kernel<<<dim3(1024), dim3(256), 0, stream>>>(rpb, rel_idx, mask, qkv_w, qkv_b,
                                                     proj_w, bm, qkv_wb, qkv_bs, proj_wb);
  fused_wattn<<<dim3(4096), dim3(512), 0, stream>>>(x, bm, qkv_bs, qkv_wb, proj_wb,
                                                    proj_b, (float*)d_out);
}

// Round 4
// 582.359 us; speedup vs baseline: 2.0180x; 1.0385x over previous
//
#include <hip/hip_runtime.h>

#define NTOK 98
#define DIMC 128

typedef __attribute__((ext_vector_type(8))) short s8v;
typedef __attribute__((ext_vector_type(4))) float f4v;

#define LOG2E 1.4426950408889634f
#define QSCALE (0.17677669529663687f * LOG2E)  // 32^-0.5 * log2(e), folded into Wq/bq

__device__ __forceinline__ ushort f2bf(float f) {
  union { float fv; unsigned u; } c; c.fv = f;
  unsigned r = c.u + 0x7fffu + ((c.u >> 16) & 1u);
  return (ushort)(r >> 16);
}
__device__ __forceinline__ unsigned pack2(float a, float b) {
  return (unsigned)f2bf(a) | ((unsigned)f2bf(b) << 16);
}

// bm tiled+padded: bm_t[w][h][it(7)][jt(7)][l16(16)][lg(4)*? ...] -- 256 floats per (it,jt)
// element (i = it*16+lg*4+r, j = jt*16+l16) stored at tile*256 + l16*16 + lg*4 + r,
// value = (mask + bias)*log2e for i<98&&j<98 else -1e30.  Size 64*4*49*1024B = 12.85 MB.
__global__ void setup_kernel(const float* __restrict__ rpb, const int* __restrict__ rel_idx,
                             const float* __restrict__ maskg,
                             const float* __restrict__ qkv_w, const float* __restrict__ qkv_b,
                             const float* __restrict__ proj_w,
                             float* __restrict__ bm, ushort* __restrict__ qkv_wb,
                             float* __restrict__ qkv_bs, ushort* __restrict__ proj_wb) {
  int tid = blockIdx.x * blockDim.x + threadIdx.x;
  int stride = gridDim.x * blockDim.x;
  const int NN = NTOK * NTOK;
  for (int idx = tid; idx < 64 * 4 * 49 * 256; idx += stride) {
    int wh = idx / (49 * 256);
    int rest = idx % (49 * 256);
    int tile = rest >> 8;           // it*7 + jt
    int e = rest & 255;
    int it = tile / 7, jt = tile % 7;
    int l16 = e >> 4, lg = (e >> 2) & 3, r = e & 3;
    int i = it * 16 + lg * 4 + r;
    int j = jt * 16 + l16;
    int w = wh >> 2, h = wh & 3;
    float v = -1e30f;
    if (i < NTOK && j < NTOK)
      v = (maskg[w * NN + i * NTOK + j] + rpb[rel_idx[i * NTOK + j] * 4 + h]) * LOG2E;
    bm[idx] = v;
  }
  for (int idx = tid; idx < 384 * DIMC; idx += stride) {
    float s = (idx < DIMC * DIMC) ? QSCALE : 1.0f;
    qkv_wb[idx] = f2bf(qkv_w[idx] * s);
  }
  for (int idx = tid; idx < 384; idx += stride)
    qkv_bs[idx] = qkv_b[idx] * ((idx < DIMC) ? QSCALE : 1.0f);
  for (int idx = tid; idx < DIMC * DIMC; idx += stride) proj_wb[idx] = f2bf(proj_w[idx]);
}

// 1024-thread block = TWO windows (threads 0-511 -> window 2*bid, 512-1023 -> 2*bid+1).
// Per window: 8 waves, waves (2h,2h+1) own head h. Per-window LDS half (34304 ushorts):
//   [0, 32768)    : x-stage [112][128] bf16 swizzled -> P [8 waves][16][128] bf16 swizzled
//   [32768, 68608): k [4][112][40] ushorts -> ao [112][128] bf16 swizzled (alias)
// 137 KB total, 1 block/CU, 16 waves/CU = 4 waves/SIMD (vs 2 at 512 threads).
// launch_bounds(1024,1): 16 waves/CU -> 4 waves/EU -> 128-VGPR cap (r3 profile fits: 124).
__global__ __launch_bounds__(1024, 1)
void fused_wattn(const float* __restrict__ x, const float* __restrict__ bm_g,
                 const float* __restrict__ qkv_bs,
                 const ushort* __restrict__ qkv_wb, const ushort* __restrict__ proj_wb,
                 const float* __restrict__ proj_b, float* __restrict__ out) {
  __shared__ ushort smem[68608];
  const int tid = threadIdx.x;
  const int win = tid >> 9;
  const int t = tid & 511;
  const int b = blockIdx.x * 2 + win;
  const int wv = (tid >> 6) & 7;
  const int lane = tid & 63;
  const int l16 = lane & 15;
  const int lg = lane >> 4;
  const int head = wv >> 1;
  const int hf = wv & 1;
  const int it0 = hf * 3;

  ushort* smw = smem + win * 34304;                    // this window's 68608-byte half
  char* xc = reinterpret_cast<char*>(smw);             // x-stage, then P region
  ushort* k_lds = smw + 16384;                         // [4][112][40]
  char* Pc = reinterpret_cast<char*>(smw) + wv * 4096;
  char* aoc = reinterpret_cast<char*>(smw + 16384);    // ao alias over k

  // ---- stage x -> bf16 LDS (swizzled), zero pad rows 98..111 ----
  {
    const float4* x4 = reinterpret_cast<const float4*>(x + (size_t)b * NTOK * DIMC);
    for (int i = t; i < 3136; i += 512) {
      float4 f = x4[i];
      uint2 u; u.x = pack2(f.x, f.y); u.y = pack2(f.z, f.w);
      int row = i >> 5;
      int off = (i * 8) ^ ((row & 7) << 4);
      *reinterpret_cast<uint2*>(xc + off) = u;
    }
    uint2 z{0u, 0u};
    for (int i = t; i < 448; i += 512)
      *reinterpret_cast<uint2*>(xc + 25088 + i * 8) = z;
  }
  __syncthreads();

  auto ldx = [&](int mt, int kc) -> s8v {
    int row = mt * 16 + l16;
    int off = (row * 256 + kc * 64 + lg * 16) ^ ((row & 7) << 4);
    return *reinterpret_cast<const s8v*>(xc + off);
  };

  const f4v fzero = {0.f, 0.f, 0.f, 0.f};

  // ---- QKV: q (swapped MFMA -> in-register A-frags via shfl) ----
  s8v qfrag[4];
  {
    s8v wq[2][4];
    float bq[2][4];
#pragma unroll
    for (int oi = 0; oi < 2; ++oi) {
      int o = 2 * head + oi;
#pragma unroll
      for (int kc = 0; kc < 4; ++kc)
        wq[oi][kc] = *reinterpret_cast<const s8v*>(&qkv_wb[(o * 16 + l16) * DIMC + kc * 32 + lg * 8]);
#pragma unroll
      for (int r = 0; r < 4; ++r) bq[oi][r] = qkv_bs[o * 16 + lg * 4 + r];
    }
#pragma unroll
    for (int ii = 0; ii < 4; ++ii) {
      int it = it0 + ii;
      s8v xf[4];
#pragma unroll
      for (int kc = 0; kc < 4; ++kc) xf[kc] = ldx(it, kc);
      f4v qs0 = fzero, qs1 = fzero;
#pragma unroll
      for (int kc = 0; kc < 4; ++kc) {
        qs0 = __builtin_amdgcn_mfma_f32_16x16x32_bf16(wq[0][kc], xf[kc], qs0, 0, 0, 0);
        qs1 = __builtin_amdgcn_mfma_f32_16x16x32_bf16(wq[1][kc], xf[kc], qs1, 0, 0, 0);
      }
#pragma unroll
      for (int r = 0; r < 4; ++r) { qs0[r] += bq[0][r]; qs1[r] += bq[1][r]; }
      float vals[8];
#pragma unroll
      for (int jj = 0; jj < 8; ++jj) {
        int srcLane = l16 + 16 * ((lg & 1) * 2 + (jj >> 2));
        float a = __shfl(qs0[jj & 3], srcLane);
        float c = __shfl(qs1[jj & 3], srcLane);
        vals[jj] = (lg & 2) ? c : a;
      }
      union { s8v v; unsigned u[4]; } tt;
      tt.u[0] = pack2(vals[0], vals[1]); tt.u[1] = pack2(vals[2], vals[3]);
      tt.u[2] = pack2(vals[4], vals[5]); tt.u[3] = pack2(vals[6], vals[7]);
      qfrag[ii] = tt.v;
    }
  }

  // ---- QKV: v (normal MFMA -> in-register B-frags via shfl over mt pairs) ----
  s8v vfrag[2][4];
  {
    s8v wv_[2][4];
    float bv[2];
#pragma unroll
    for (int oi = 0; oi < 2; ++oi) {
      int o = 16 + 2 * head + oi;
#pragma unroll
      for (int kc = 0; kc < 4; ++kc)
        wv_[oi][kc] = *reinterpret_cast<const s8v*>(&qkv_wb[(o * 16 + l16) * DIMC + kc * 32 + lg * 8]);
      bv[oi] = qkv_bs[256 + head * 32 + oi * 16 + l16];
    }
#pragma unroll
    for (int mtp = 0; mtp < 4; ++mtp) {
      f4v accA[2] = {fzero, fzero}, accB[2] = {fzero, fzero};
      {
        s8v xf[4];
#pragma unroll
        for (int kc = 0; kc < 4; ++kc) xf[kc] = ldx(2 * mtp, kc);
#pragma unroll
        for (int kc = 0; kc < 4; ++kc) {
          accA[0] = __builtin_amdgcn_mfma_f32_16x16x32_bf16(xf[kc], wv_[0][kc], accA[0], 0, 0, 0);
          accA[1] = __builtin_amdgcn_mfma_f32_16x16x32_bf16(xf[kc], wv_[1][kc], accA[1], 0, 0, 0);
        }
#pragma unroll
        for (int r = 0; r < 4; ++r) { accA[0][r] += bv[0]; accA[1][r] += bv[1]; }
      }
      if (mtp < 3) {
        s8v xf[4];
#pragma unroll
        for (int kc = 0; kc < 4; ++kc) xf[kc] = ldx(2 * mtp + 1, kc);
#pragma unroll
        for (int kc = 0; kc < 4; ++kc) {
          accB[0] = __builtin_amdgcn_mfma_f32_16x16x32_bf16(xf[kc], wv_[0][kc], accB[0], 0, 0, 0);
          accB[1] = __builtin_amdgcn_mfma_f32_16x16x32_bf16(xf[kc], wv_[1][kc], accB[1], 0, 0, 0);
        }
#pragma unroll
        for (int r = 0; r < 4; ++r) { accB[0][r] += bv[0]; accB[1][r] += bv[1]; }
      }
#pragma unroll
      for (int oi = 0; oi < 2; ++oi) {
        float vals[8];
#pragma unroll
        for (int jj = 0; jj < 8; ++jj) {
          int srcLane = l16 + 16 * ((lg & 1) * 2 + (jj >> 2));
          float a = __shfl(accA[oi][jj & 3], srcLane);
          float c = __shfl(accB[oi][jj & 3], srcLane);
          vals[jj] = (lg & 2) ? c : a;
        }
        union { s8v v; unsigned u[4]; } tt;
        tt.u[0] = pack2(vals[0], vals[1]); tt.u[1] = pack2(vals[2], vals[3]);
        tt.u[2] = pack2(vals[4], vals[5]); tt.u[3] = pack2(vals[6], vals[7]);
        vfrag[oi][mtp] = tt.v;
      }
    }
  }

  // ---- QKV: k -> LDS (wave owns k-otile wv; 80 B rows) ----
  {
    s8v wk[4];
#pragma unroll
    for (int kc = 0; kc < 4; ++kc)
      wk[kc] = *reinterpret_cast<const s8v*>(&qkv_wb[((8 + wv) * 16 + l16) * DIMC + kc * 32 + lg * 8]);
    float bk = qkv_bs[128 + wv * 16 + l16];
    ushort* kdst = k_lds + (wv >> 1) * (112 * 40) + (wv & 1) * 16 + l16;
#pragma unroll
    for (int mt = 0; mt < 7; ++mt) {
      f4v acc = fzero;
#pragma unroll
      for (int kc = 0; kc < 4; ++kc)
        acc = __builtin_amdgcn_mfma_f32_16x16x32_bf16(ldx(mt, kc), wk[kc], acc, 0, 0, 0);
#pragma unroll
      for (int r = 0; r < 4; ++r)
        kdst[(mt * 16 + lg * 4 + r) * 40] = f2bf(acc[r] + bk);
    }
  }
  __syncthreads();  // k ready; x region dead -> P may be written

  // zero this wave's P pad cols 112..127
  for (int idx = lane; idx < 256; idx += 64) {
    int rw = idx >> 4, cl = 112 + (idx & 15);
    int off = (rw * 256 + cl * 2) ^ ((rw & 7) << 4);
    *reinterpret_cast<ushort*>(Pc + off) = 0;
  }

  // ---- attention ----
  const float* bmt = bm_g + (size_t)(((b & 63) * 4 + head) * 49) * 256;
  const int bmoff = l16 * 16 + lg * 4;
  f4v oacc[4][2];
#pragma unroll
  for (int ii = 0; ii < 4; ++ii) {
    const int it = it0 + ii;
    f4v S[7];
#pragma unroll
    for (int jt = 0; jt < 7; ++jt) {
      s8v kf = *reinterpret_cast<const s8v*>(&k_lds[(head * 112 + jt * 16 + l16) * 40 + lg * 8]);
      S[jt] = __builtin_amdgcn_mfma_f32_16x16x32_bf16(qfrag[ii], kf, fzero, 0, 0, 0);
    }
    // + (bias+mask)*log2e with -1e30 pads baked in (coalesced float4 per lane)
#pragma unroll
    for (int jt = 0; jt < 7; ++jt) {
      f4v bmv = *reinterpret_cast<const f4v*>(&bmt[(it * 7 + jt) * 256 + bmoff]);
      S[jt] = S[jt] + bmv;
    }
    float srow[4];
#pragma unroll
    for (int r = 0; r < 4; ++r) {
      float m = S[0][r];
#pragma unroll
      for (int jt = 1; jt < 7; ++jt) m = fmaxf(m, S[jt][r]);
      m = fmaxf(m, __shfl_xor(m, 1));
      m = fmaxf(m, __shfl_xor(m, 2));
      m = fmaxf(m, __shfl_xor(m, 4));
      m = fmaxf(m, __shfl_xor(m, 8));
      float s = 0.f;
#pragma unroll
      for (int jt = 0; jt < 7; ++jt) {
        float p = exp2f(S[jt][r] - m);
        S[jt][r] = p;
        s += p;
      }
      s += __shfl_xor(s, 1);
      s += __shfl_xor(s, 2);
      s += __shfl_xor(s, 4);
      s += __shfl_xor(s, 8);
      srow[r] = s;
    }
    // P -> LDS bf16 (swizzled)
#pragma unroll
    for (int r = 0; r < 4; ++r) {
      int rw = lg * 4 + r;
#pragma unroll
      for (int jt = 0; jt < 7; ++jt) {
        int off = (rw * 256 + (jt * 16 + l16) * 2) ^ ((rw & 7) << 4);
        *reinterpret_cast<ushort*>(Pc + off) = f2bf(S[jt][r]);
      }
    }
    asm volatile("s_waitcnt lgkmcnt(0)" ::: "memory");
    f4v o0 = fzero, o1 = fzero;
#pragma unroll
    for (int kc = 0; kc < 4; ++kc) {
      int off = (l16 * 256 + kc * 64 + lg * 16) ^ ((l16 & 7) << 4);
      s8v pf = *reinterpret_cast<const s8v*>(Pc + off);
      o0 = __builtin_amdgcn_mfma_f32_16x16x32_bf16(pf, vfrag[0][kc], o0, 0, 0, 0);
      o1 = __builtin_amdgcn_mfma_f32_16x16x32_bf16(pf, vfrag[1][kc], o1, 0, 0, 0);
    }
#pragma unroll
    for (int r = 0; r < 4; ++r) {
      float inv = 1.0f / srow[r];
      o0[r] *= inv; o1[r] *= inv;
    }
    oacc[ii][0] = o0; oacc[ii][1] = o1;
  }
  __syncthreads();  // all k reads done -> ao may alias k region

  // ---- attn-out -> LDS bf16 (swizzled) ----
#pragma unroll
  for (int ii = 0; ii < 4; ++ii) {
    int it = it0 + ii;
#pragma unroll
    for (int r = 0; r < 4; ++r) {
      int n = it * 16 + lg * 4 + r;
      if (n < NTOK) {
        int c0 = head * 32 + l16;
        *reinterpret_cast<ushort*>(aoc + ((n * 256 + c0 * 2) ^ ((n & 7) << 4))) = f2bf(oacc[ii][0][r]);
        int c1 = c0 + 16;
        *reinterpret_cast<ushort*>(aoc + ((n * 256 + c1 * 2) ^ ((n & 7) << 4))) = f2bf(oacc[ii][1][r]);
      }
    }
  }
  __syncthreads();

  // ---- proj: wave ww owns rows [16ww,16ww+16) -> full 512 B out-row writes ----
  if (wv < 7) {
    float* outb = out + (size_t)b * NTOK * DIMC;
    const int row = wv * 16 + l16;
#pragma unroll
    for (int ot = 0; ot < 8; ++ot) {
      s8v pw[4];
#pragma unroll
      for (int kc = 0; kc < 4; ++kc)
        pw[kc] = *reinterpret_cast<const s8v*>(&proj_wb[(ot * 16 + l16) * DIMC + kc * 32 + lg * 8]);
      float pb = proj_b[ot * 16 + l16];
      f4v acc = fzero;
#pragma unroll
      for (int kc = 0; kc < 4; ++kc) {
        int off = (row * 256 + kc * 64 + lg * 16) ^ ((row & 7) << 4);
        s8v af = *reinterpret_cast<const s8v*>(aoc + off);
        acc = __builtin_amdgcn_mfma_f32_16x16x32_bf16(af, pw[kc], acc, 0, 0, 0);
      }
#pragma unroll
      for (int r = 0; r < 4; ++r) {
        int n = wv * 16 + lg * 4 + r;
        if (n < NTOK) outb[n * DIMC + ot * 16 + l16] = acc[r] + pb;
      }
    }
  }
}

extern "C" void kernel_launch(void* const* d_in, const int* in_sizes, int n_in,
                              void* d_out, int out_size, void* d_ws, size_t ws_size,
                              hipStream_t stream) {
  const float* x = (const float*)d_in[0];
  const float* mask = (const float*)d_in[1];
  const float* rpb = (const float*)d_in[2];
  const float* qkv_w = (const float*)d_in[3];
  const float* qkv_b = (const float*)d_in[4];
  const float* proj_w = (const float*)d_in[5];
  const float* proj_b = (const float*)d_in[6];
  const int* rel_idx = (const int*)d_in[7];

  char* ws = (char*)d_ws;
  float* bm = (float*)ws;                                   // 64*4*49*1024 = 12,845,056 B
  ushort* qkv_wb = (ushort*)(ws + 12845056);                // 384*128*2    =     98,304 B
  float* qkv_bs = (float*)(ws + 12845056 + 98304);          // 384*4        =      1,536 B
  ushort* proj_wb = (ushort*)(ws + 12845056 + 98304 + 1536);// 128*128*2    =     32,768 B

  setup_kernel<<<dim3(1024), dim3(256), 0, stream>>>(rpb, rel_idx, mask, qkv_w, qkv_b,
                                                     proj_w, bm, qkv_wb, qkv_bs, proj_wb);
  fused_wattn<<<dim3(2048), dim3(1024), 0, stream>>>(x, bm, qkv_bs, qkv_wb, proj_wb,
                                                     proj_b, (float*)d_out);
}

// Round 6
// 488.006 us; speedup vs baseline: 2.4082x; 1.1933x over previous
//
#include <hip/hip_runtime.h>

#define NTOK 98
#define DIMC 128

typedef __attribute__((ext_vector_type(8))) short s8v;
typedef __attribute__((ext_vector_type(4))) float f4v;

#define LOG2E 1.4426950408889634f
#define QSCALE (0.17677669529663687f * LOG2E)  // 32^-0.5 * log2(e), folded into Wq/bq

__device__ __forceinline__ ushort f2bf(float f) {
  union { float fv; unsigned u; } c; c.fv = f;
  unsigned r = c.u + 0x7fffu + ((c.u >> 16) & 1u);
  return (ushort)(r >> 16);
}
__device__ __forceinline__ unsigned pack2(float a, float b) {
  return (unsigned)f2bf(a) | ((unsigned)f2bf(b) << 16);
}

// bm tiled+padded (as r4): bm[w][h][it][jt][256 floats]; element (i=it*16+lg*4+r,
// j=jt*16+l16) at tile*256 + l16*16 + lg*4 + r; -1e30 baked for i>=98 or j>=98.
__global__ void setup_kernel(const float* __restrict__ rpb, const int* __restrict__ rel_idx,
                             const float* __restrict__ maskg,
                             const float* __restrict__ qkv_w, const float* __restrict__ qkv_b,
                             const float* __restrict__ proj_w,
                             float* __restrict__ bm, ushort* __restrict__ qkv_wb,
                             float* __restrict__ qkv_bs, ushort* __restrict__ proj_wb) {
  int tid = blockIdx.x * blockDim.x + threadIdx.x;
  int stride = gridDim.x * blockDim.x;
  const int NN = NTOK * NTOK;
  for (int idx = tid; idx < 64 * 4 * 49 * 256; idx += stride) {
    int wh = idx / (49 * 256);
    int rest = idx % (49 * 256);
    int tile = rest >> 8;
    int e = rest & 255;
    int it = tile / 7, jt = tile % 7;
    int l16 = e >> 4, lg = (e >> 2) & 3, r = e & 3;
    int i = it * 16 + lg * 4 + r;
    int j = jt * 16 + l16;
    int w = wh >> 2, h = wh & 3;
    float v = -1e30f;
    if (i < NTOK && j < NTOK)
      v = (maskg[w * NN + i * NTOK + j] + rpb[rel_idx[i * NTOK + j] * 4 + h]) * LOG2E;
    bm[idx] = v;
  }
  for (int idx = tid; idx < 384 * DIMC; idx += stride) {
    float s = (idx < DIMC * DIMC) ? QSCALE : 1.0f;
    qkv_wb[idx] = f2bf(qkv_w[idx] * s);
  }
  for (int idx = tid; idx < 384; idx += stride)
    qkv_bs[idx] = qkv_b[idx] * ((idx < DIMC) ? QSCALE : 1.0f);
  for (int idx = tid; idx < DIMC * DIMC; idx += stride) proj_wb[idx] = f2bf(proj_w[idx]);
}

// 256-thread block = ONE window, wave w = head w (4 waves).
// LDS 53760 B -> 3 blocks/CU (161280 <= 163840); regs target <=170 total -> 3 waves/EU.
//   R1 [0,25088): x [98][128] bf16 swizzled -> P [4 waves][16][128] (16 KB, over x rows 0-63)
//                 -> ao [98][128] bf16 swizzled (after attention barrier)
//   R2 [25088,53760): k frag-major [head 4][mt 7][lane 64][16 B]; consumer ds_read_b128 at
//                 lane*16 = conflict-free, zero padding.
// x reads at rows 98-111 (mt==6, l16>=2) land in R2 = UNINITIALIZED LDS -> possibly
// Inf/NaN bf16 (r5 NaN failure: NaN k-cols poison valid rows via NaN+(-1e30); 0*Inf in PV).
// Fix: zero those fragments IN REGISTERS (ldx mask, compile-time mt==6 case). Then pad
// tokens carry bias-only finite values and r4's masking invariants hold:
// k pad -> bm=-1e30 -> P=0; v pad finite * P=0 -> 0; junk out rows write-guarded.
// Register/occupancy empirics (r1-r4): residency gated by TOTAL (arch+acc) regs;
// 512-thread blocks quantize to 8/16 waves per CU and 16 needs total<=128 (unreachable
// without spill: r2/r4). 256-thread blocks + total<=170 -> 12 waves/CU.
__global__ __launch_bounds__(256) __attribute__((amdgpu_waves_per_eu(3)))
void fused_wattn(const float* __restrict__ x, const float* __restrict__ bm_g,
                 const float* __restrict__ qkv_bs,
                 const ushort* __restrict__ qkv_wb, const ushort* __restrict__ proj_wb,
                 const float* __restrict__ proj_b, float* __restrict__ out) {
  __shared__ ushort smem[26880];
  const int b = blockIdx.x;
  const int tid = threadIdx.x;
  const int h = tid >> 6;      // wave index == head
  const int lane = tid & 63;
  const int l16 = lane & 15;
  const int lg = lane >> 4;

  char* xc = reinterpret_cast<char*>(smem);
  char* Pc = reinterpret_cast<char*>(smem) + h * 4096;
  char* aoc = reinterpret_cast<char*>(smem);
  char* kfb = reinterpret_cast<char*>(smem) + 25088 + h * 7168;  // this head's k frags

  // ---- stage x -> bf16 LDS (swizzled), rows 0..97 only ----
  {
    const float4* x4 = reinterpret_cast<const float4*>(x + (size_t)b * NTOK * DIMC);
    for (int i = tid; i < 3136; i += 256) {
      float4 f = x4[i];
      uint2 u; u.x = pack2(f.x, f.y); u.y = pack2(f.z, f.w);
      int row = i >> 5;
      *reinterpret_cast<uint2*>(xc + ((i * 8) ^ ((row & 7) << 4))) = u;
    }
  }
  __syncthreads();

  // mt is compile-time at every call site (unrolled loops) -> the mt==6 mask folds away
  // for mt<6 and becomes 4 cndmasks for mt==6.
  auto ldx = [&](int mt, int kc) -> s8v {
    int row = mt * 16 + l16;
    int off = (row * 256 + kc * 64 + lg * 16) ^ ((row & 7) << 4);
    s8v v = *reinterpret_cast<const s8v*>(xc + off);
    if (mt == 6 && l16 >= 2) {        // rows 98..111: reads hit junk LDS -> force 0
      s8v z = {0, 0, 0, 0, 0, 0, 0, 0};
      v = z;
    }
    return v;
  };

  const f4v fzero = {0.f, 0.f, 0.f, 0.f};

  // ---- QKV q: swapped MFMA -> in-register A-frags via shfl (7 itiles) ----
  s8v qfrag[7];
  {
    s8v wq[2][4];
    float bq[2][4];
#pragma unroll
    for (int oi = 0; oi < 2; ++oi) {
      int o = 2 * h + oi;
#pragma unroll
      for (int kc = 0; kc < 4; ++kc)
        wq[oi][kc] = *reinterpret_cast<const s8v*>(&qkv_wb[(o * 16 + l16) * DIMC + kc * 32 + lg * 8]);
#pragma unroll
      for (int r = 0; r < 4; ++r) bq[oi][r] = qkv_bs[o * 16 + lg * 4 + r];
    }
#pragma unroll
    for (int ii = 0; ii < 7; ++ii) {
      s8v xf[4];
#pragma unroll
      for (int kc = 0; kc < 4; ++kc) xf[kc] = ldx(ii, kc);
      f4v qs0 = fzero, qs1 = fzero;
#pragma unroll
      for (int kc = 0; kc < 4; ++kc) {
        qs0 = __builtin_amdgcn_mfma_f32_16x16x32_bf16(wq[0][kc], xf[kc], qs0, 0, 0, 0);
        qs1 = __builtin_amdgcn_mfma_f32_16x16x32_bf16(wq[1][kc], xf[kc], qs1, 0, 0, 0);
      }
#pragma unroll
      for (int r = 0; r < 4; ++r) { qs0[r] += bq[0][r]; qs1[r] += bq[1][r]; }
      float vals[8];
#pragma unroll
      for (int jj = 0; jj < 8; ++jj) {
        int srcLane = l16 + 16 * ((lg & 1) * 2 + (jj >> 2));
        float a = __shfl(qs0[jj & 3], srcLane);
        float c = __shfl(qs1[jj & 3], srcLane);
        vals[jj] = (lg & 2) ? c : a;
      }
      union { s8v v; unsigned u[4]; } tt;
      tt.u[0] = pack2(vals[0], vals[1]); tt.u[1] = pack2(vals[2], vals[3]);
      tt.u[2] = pack2(vals[4], vals[5]); tt.u[3] = pack2(vals[6], vals[7]);
      qfrag[ii] = tt.v;
    }
  }

  // ---- QKV v: normal MFMA -> in-register B-frags via shfl; one oi at a time ----
  s8v vfrag[2][4];
#pragma unroll
  for (int oi = 0; oi < 2; ++oi) {
    s8v wvv[4];
    int o = 16 + 2 * h + oi;
#pragma unroll
    for (int kc = 0; kc < 4; ++kc)
      wvv[kc] = *reinterpret_cast<const s8v*>(&qkv_wb[(o * 16 + l16) * DIMC + kc * 32 + lg * 8]);
    float bv = qkv_bs[256 + h * 32 + oi * 16 + l16];
#pragma unroll
    for (int mtp = 0; mtp < 4; ++mtp) {
      f4v accA = fzero, accB = fzero;
      {
        s8v xf[4];
#pragma unroll
        for (int kc = 0; kc < 4; ++kc) xf[kc] = ldx(2 * mtp, kc);
#pragma unroll
        for (int kc = 0; kc < 4; ++kc)
          accA = __builtin_amdgcn_mfma_f32_16x16x32_bf16(xf[kc], wvv[kc], accA, 0, 0, 0);
#pragma unroll
        for (int r = 0; r < 4; ++r) accA[r] += bv;
      }
      if (mtp < 3) {  // mt=7 absent; tokens 112..127 stay 0 (P cols there are 0)
        s8v xf[4];
#pragma unroll
        for (int kc = 0; kc < 4; ++kc) xf[kc] = ldx(2 * mtp + 1, kc);
#pragma unroll
        for (int kc = 0; kc < 4; ++kc)
          accB = __builtin_amdgcn_mfma_f32_16x16x32_bf16(xf[kc], wvv[kc], accB, 0, 0, 0);
#pragma unroll
        for (int r = 0; r < 4; ++r) accB[r] += bv;
      }
      float vals[8];
#pragma unroll
      for (int jj = 0; jj < 8; ++jj) {
        int srcLane = l16 + 16 * ((lg & 1) * 2 + (jj >> 2));
        float a = __shfl(accA[jj & 3], srcLane);
        float c = __shfl(accB[jj & 3], srcLane);
        vals[jj] = (lg & 2) ? c : a;   // lg>>1 picks mt parity
      }
      union { s8v v; unsigned u[4]; } tt;
      tt.u[0] = pack2(vals[0], vals[1]); tt.u[1] = pack2(vals[2], vals[3]);
      tt.u[2] = pack2(vals[4], vals[5]); tt.u[3] = pack2(vals[6], vals[7]);
      vfrag[oi][mtp] = tt.v;
    }
  }

  // ---- QKV k -> LDS frag-major; one ko (16-chan tile) at a time ----
#pragma unroll
  for (int ko = 0; ko < 2; ++ko) {
    s8v wk[4];
    int o = 8 + 2 * h + ko;
#pragma unroll
    for (int kc = 0; kc < 4; ++kc)
      wk[kc] = *reinterpret_cast<const s8v*>(&qkv_wb[(o * 16 + l16) * DIMC + kc * 32 + lg * 8]);
    float bk = qkv_bs[128 + (2 * h + ko) * 16 + l16];
    // producer lane holds (token=mt*16+lg*4+r, chan=ko*16+l16); frag dest:
    // byte = mt*1024 + (lg*4+r)*16 + (ko*2+(l16>>3))*256 + (l16&7)*2
    char* kw = kfb + (ko * 2 + (l16 >> 3)) * 256 + (l16 & 7) * 2 + (lg * 4) * 16;
#pragma unroll
    for (int mt = 0; mt < 7; ++mt) {
      f4v acc = fzero;
#pragma unroll
      for (int kc = 0; kc < 4; ++kc)
        acc = __builtin_amdgcn_mfma_f32_16x16x32_bf16(ldx(mt, kc), wk[kc], acc, 0, 0, 0);
#pragma unroll
      for (int r = 0; r < 4; ++r)
        *reinterpret_cast<ushort*>(kw + mt * 1024 + r * 16) = f2bf(acc[r] + bk);
    }
  }
  __syncthreads();  // QKV done: x dead -> P writable; k frags ready

  // zero this wave's P pad cols 112..127 (persist across all ii)
  for (int idx = lane; idx < 256; idx += 64) {
    int rw = idx >> 4, cl = 112 + (idx & 15);
    int off = (rw * 256 + cl * 2) ^ ((rw & 7) << 4);
    *reinterpret_cast<ushort*>(Pc + off) = 0;
  }

  // ---- attention: 7 itiles, this head only ----
  const float* bmt = bm_g + (size_t)(((b & 63) * 4 + h) * 49) * 256;
  const int bmoff = l16 * 16 + lg * 4;
  unsigned oaccp[7][4];
#pragma unroll
  for (int ii = 0; ii < 7; ++ii) {
    f4v bmv[7];
#pragma unroll
    for (int jt = 0; jt < 7; ++jt)
      bmv[jt] = *reinterpret_cast<const f4v*>(&bmt[(ii * 7 + jt) * 256 + bmoff]);
    f4v S[7];
#pragma unroll
    for (int jt = 0; jt < 7; ++jt) {
      s8v kf = *reinterpret_cast<const s8v*>(kfb + jt * 1024 + lane * 16);
      S[jt] = __builtin_amdgcn_mfma_f32_16x16x32_bf16(qfrag[ii], kf, fzero, 0, 0, 0);
    }
#pragma unroll
    for (int jt = 0; jt < 7; ++jt) S[jt] = S[jt] + bmv[jt];
    float srow[4];
#pragma unroll
    for (int r = 0; r < 4; ++r) {
      float m = S[0][r];
#pragma unroll
      for (int jt = 1; jt < 7; ++jt) m = fmaxf(m, S[jt][r]);
      m = fmaxf(m, __shfl_xor(m, 1));
      m = fmaxf(m, __shfl_xor(m, 2));
      m = fmaxf(m, __shfl_xor(m, 4));
      m = fmaxf(m, __shfl_xor(m, 8));
      float s = 0.f;
#pragma unroll
      for (int jt = 0; jt < 7; ++jt) {
        float p = exp2f(S[jt][r] - m);
        S[jt][r] = p;
        s += p;
      }
      s += __shfl_xor(s, 1);
      s += __shfl_xor(s, 2);
      s += __shfl_xor(s, 4);
      s += __shfl_xor(s, 8);
      srow[r] = s;
    }
    // P -> LDS bf16 (swizzled)
#pragma unroll
    for (int r = 0; r < 4; ++r) {
      int rw = lg * 4 + r;
#pragma unroll
      for (int jt = 0; jt < 7; ++jt) {
        int off = (rw * 256 + (jt * 16 + l16) * 2) ^ ((rw & 7) << 4);
        *reinterpret_cast<ushort*>(Pc + off) = f2bf(S[jt][r]);
      }
    }
    asm volatile("s_waitcnt lgkmcnt(0)" ::: "memory");
    f4v o0 = fzero, o1 = fzero;
#pragma unroll
    for (int kc = 0; kc < 4; ++kc) {
      int off = (l16 * 256 + kc * 64 + lg * 16) ^ ((l16 & 7) << 4);
      s8v pf = *reinterpret_cast<const s8v*>(Pc + off);
      o0 = __builtin_amdgcn_mfma_f32_16x16x32_bf16(pf, vfrag[0][kc], o0, 0, 0, 0);
      o1 = __builtin_amdgcn_mfma_f32_16x16x32_bf16(pf, vfrag[1][kc], o1, 0, 0, 0);
    }
    float inv0 = 1.0f / srow[0], inv1 = 1.0f / srow[1];
    float inv2 = 1.0f / srow[2], inv3 = 1.0f / srow[3];
    oaccp[ii][0] = pack2(o0[0] * inv0, o0[1] * inv1);
    oaccp[ii][1] = pack2(o0[2] * inv2, o0[3] * inv3);
    oaccp[ii][2] = pack2(o1[0] * inv0, o1[1] * inv1);
    oaccp[ii][3] = pack2(o1[2] * inv2, o1[3] * inv3);
  }
  __syncthreads();  // all PV done -> P/k dead -> ao writable over R1

  // ---- attn-out -> LDS bf16 (swizzled): rows = this wave's itiles, cols [32h,32h+32) ----
#pragma unroll
  for (int ii = 0; ii < 7; ++ii) {
#pragma unroll
    for (int r = 0; r < 4; ++r) {
      int n = ii * 16 + lg * 4 + r;
      if (n < NTOK) {
        ushort v0 = (ushort)(oaccp[ii][(r >> 1)] >> (16 * (r & 1)));
        ushort v1 = (ushort)(oaccp[ii][2 + (r >> 1)] >> (16 * (r & 1)));
        int c0 = h * 32 + l16;
        *reinterpret_cast<ushort*>(aoc + ((n * 256 + c0 * 2) ^ ((n & 7) << 4))) = v0;
        int c1 = c0 + 16;
        *reinterpret_cast<ushort*>(aoc + ((n * 256 + c1 * 2) ^ ((n & 7) << 4))) = v1;
      }
    }
  }
  __syncthreads();

  // ---- proj: wave h owns row-tiles {h, h+4}; ao reads of rows 98-111 hit the dead k-frag
  // region (finite bf16, fully written during QKV) -> junk only in write-guarded rows ----
  float* outb = out + (size_t)b * NTOK * DIMC;
#pragma unroll
  for (int pass = 0; pass < 2; ++pass) {
    int rt = h + pass * 4;
    if (rt < 7) {
      const int row = rt * 16 + l16;
#pragma unroll
      for (int ot = 0; ot < 8; ++ot) {
        s8v pw[4];
#pragma unroll
        for (int kc = 0; kc < 4; ++kc)
          pw[kc] = *reinterpret_cast<const s8v*>(&proj_wb[(ot * 16 + l16) * DIMC + kc * 32 + lg * 8]);
        float pb = proj_b[ot * 16 + l16];
        f4v acc = fzero;
#pragma unroll
        for (int kc = 0; kc < 4; ++kc) {
          int off = (row * 256 + kc * 64 + lg * 16) ^ ((row & 7) << 4);
          s8v af = *reinterpret_cast<const s8v*>(aoc + off);
          acc = __builtin_amdgcn_mfma_f32_16x16x32_bf16(af, pw[kc], acc, 0, 0, 0);
        }
#pragma unroll
        for (int r = 0; r < 4; ++r) {
          int n = rt * 16 + lg * 4 + r;
          if (n < NTOK) outb[n * DIMC + ot * 16 + l16] = acc[r] + pb;
        }
      }
    }
  }
}

extern "C" void kernel_launch(void* const* d_in, const int* in_sizes, int n_in,
                              void* d_out, int out_size, void* d_ws, size_t ws_size,
                              hipStream_t stream) {
  const float* x = (const float*)d_in[0];
  const float* mask = (const float*)d_in[1];
  const float* rpb = (const float*)d_in[2];
  const float* qkv_w = (const float*)d_in[3];
  const float* qkv_b = (const float*)d_in[4];
  const float* proj_w = (const float*)d_in[5];
  const float* proj_b = (const float*)d_in[6];
  const int* rel_idx = (const int*)d_in[7];

  char* ws = (char*)d_ws;
  float* bm = (float*)ws;                                   // 64*4*49*1024 = 12,845,056 B
  ushort* qkv_wb = (ushort*)(ws + 12845056);                // 384*128*2    =     98,304 B
  float* qkv_bs = (float*)(ws + 12845056 + 98304);          // 384*4        =      1,536 B
  ushort* proj_wb = (ushort*)(ws + 12845056 + 98304 + 1536);// 128*128*2    =     32,768 B

  setup_kernel<<<dim3(1024), dim3(256), 0, stream>>>(rpb, rel_idx, mask, qkv_w, qkv_b,
                                                     proj_w, bm, qkv_wb, qkv_bs, proj_wb);
  fused_wattn<<<dim3(4096), dim3(256), 0, stream>>>(x, bm, qkv_bs, qkv_wb, proj_wb,
                                                    proj_b, (float*)d_out);
}

// Round 7
// 440.406 us; speedup vs baseline: 2.6685x; 1.1081x over previous
//
#include <hip/hip_runtime.h>

#define NTOK 98
#define DIMC 128

typedef __attribute__((ext_vector_type(8))) short s8v;
typedef __attribute__((ext_vector_type(4))) float f4v;

#define LOG2E 1.4426950408889634f
#define QSCALE (0.17677669529663687f * LOG2E)  // 32^-0.5 * log2(e), folded into Wq/bq

__device__ __forceinline__ ushort f2bf(float f) {
  union { float fv; unsigned u; } c; c.fv = f;
  unsigned r = c.u + 0x7fffu + ((c.u >> 16) & 1u);
  return (ushort)(r >> 16);
}
__device__ __forceinline__ unsigned pack2(float a, float b) {
  return (unsigned)f2bf(a) | ((unsigned)f2bf(b) << 16);
}

// bm tiled+padded, TRANSPOSED mapping (matches S_T = K@Q^T C-layout):
// element at tile(it,jt)*256 + l16*16 + lg*4 + r  is for  i = it*16 + l16 (q row),
// j = jt*16 + lg*4 + r (k col); -1e30 baked for i>=98 or j>=98.
__global__ void setup_kernel(const float* __restrict__ rpb, const int* __restrict__ rel_idx,
                             const float* __restrict__ maskg,
                             const float* __restrict__ qkv_w, const float* __restrict__ qkv_b,
                             const float* __restrict__ proj_w,
                             float* __restrict__ bm, ushort* __restrict__ qkv_wb,
                             float* __restrict__ qkv_bs, ushort* __restrict__ proj_wb) {
  int tid = blockIdx.x * blockDim.x + threadIdx.x;
  int stride = gridDim.x * blockDim.x;
  const int NN = NTOK * NTOK;
  for (int idx = tid; idx < 64 * 4 * 49 * 256; idx += stride) {
    int wh = idx / (49 * 256);
    int rest = idx % (49 * 256);
    int tile = rest >> 8;
    int e = rest & 255;
    int it = tile / 7, jt = tile % 7;
    int l16 = e >> 4, lg = (e >> 2) & 3, r = e & 3;
    int i = it * 16 + l16;            // TRANSPOSED: i from l16
    int j = jt * 16 + lg * 4 + r;     //             j from (lg, r)
    int w = wh >> 2, h = wh & 3;
    float v = -1e30f;
    if (i < NTOK && j < NTOK)
      v = (maskg[w * NN + i * NTOK + j] + rpb[rel_idx[i * NTOK + j] * 4 + h]) * LOG2E;
    bm[idx] = v;
  }
  for (int idx = tid; idx < 384 * DIMC; idx += stride) {
    float s = (idx < DIMC * DIMC) ? QSCALE : 1.0f;
    qkv_wb[idx] = f2bf(qkv_w[idx] * s);
  }
  for (int idx = tid; idx < 384; idx += stride)
    qkv_bs[idx] = qkv_b[idx] * ((idx < DIMC) ? QSCALE : 1.0f);
  for (int idx = tid; idx < DIMC * DIMC; idx += stride) proj_wb[idx] = f2bf(proj_w[idx]);
}

// 256-thread block = ONE window, wave = head (4 waves). LDS 53760 B -> 3 blocks/CU.
//   R1 [0,25088):  x [98][128] bf16 swizzled -> ao [98][128] bf16 swizzled (x dead after QKV;
//                  P never goes to LDS in this version -> ao written during attention)
//   R2 [25088,53760): k frag-major [head 4][jt 7][lane 64][16 B]; ds_read_b128 conflict-free.
// TRANSPOSED attention: S_T = mfma(A=kf, B=qfrag) -> lane l16 holds q-row i, regs span k-cols.
//  - softmax lane-local: 2 shfl_xor for max + 2 for sum (was 32 shfls)
//  - PV A-frags built in-register (same shfl/cndmask transform as q; register index is
//    compile-time ONLY in this transposed layout)
//  - ao written per-itile right after PV -> no oaccp[7][4] (-28 regs), no P LDS, no
//    lgkmcnt stall, no P pad zeroing (j>=98 pads free via baked -1e30 bias)
// Register/occupancy empirics (r1-r6): waves_per_eu(3) caps TOTAL (arch+acc) ~168; r6's
// ~200-reg demand spilled ~840 MB. This version's demand ~150 -> expect no spill.
__global__ __launch_bounds__(256) __attribute__((amdgpu_waves_per_eu(3)))
void fused_wattn(const float* __restrict__ x, const float* __restrict__ bm_g,
                 const float* __restrict__ qkv_bs,
                 const ushort* __restrict__ qkv_wb, const ushort* __restrict__ proj_wb,
                 const float* __restrict__ proj_b, float* __restrict__ out) {
  __shared__ ushort smem[26880];
  const int b = blockIdx.x;
  const int tid = threadIdx.x;
  const int h = tid >> 6;      // wave index == head
  const int lane = tid & 63;
  const int l16 = lane & 15;
  const int lg = lane >> 4;

  char* xc = reinterpret_cast<char*>(smem);
  char* aoc = reinterpret_cast<char*>(smem);
  char* kfb = reinterpret_cast<char*>(smem) + 25088 + h * 7168;  // this head's k frags

  // ---- stage x -> bf16 LDS (swizzled), rows 0..97 only ----
  {
    const float4* x4 = reinterpret_cast<const float4*>(x + (size_t)b * NTOK * DIMC);
    for (int i = tid; i < 3136; i += 256) {
      float4 f = x4[i];
      uint2 u; u.x = pack2(f.x, f.y); u.y = pack2(f.z, f.w);
      int row = i >> 5;
      *reinterpret_cast<uint2*>(xc + ((i * 8) ^ ((row & 7) << 4))) = u;
    }
  }
  __syncthreads();

  // mt==6, l16>=2 reads rows 98..111 -> junk LDS (k region, unwritten at q/v time);
  // force 0 in registers (possibly-Inf/NaN junk caused r5's failure).
  auto ldx = [&](int mt, int kc) -> s8v {
    int row = mt * 16 + l16;
    int off = (row * 256 + kc * 64 + lg * 16) ^ ((row & 7) << 4);
    s8v v = *reinterpret_cast<const s8v*>(xc + off);
    if (mt == 6 && l16 >= 2) {
      s8v z = {0, 0, 0, 0, 0, 0, 0, 0};
      v = z;
    }
    return v;
  };

  const f4v fzero = {0.f, 0.f, 0.f, 0.f};

  // ---- QKV q: swapped MFMA -> in-register A/B-frags via shfl (7 itiles) ----
  s8v qfrag[7];
  {
    s8v wq[2][4];
    float bq[2][4];
#pragma unroll
    for (int oi = 0; oi < 2; ++oi) {
      int o = 2 * h + oi;
#pragma unroll
      for (int kc = 0; kc < 4; ++kc)
        wq[oi][kc] = *reinterpret_cast<const s8v*>(&qkv_wb[(o * 16 + l16) * DIMC + kc * 32 + lg * 8]);
#pragma unroll
      for (int r = 0; r < 4; ++r) bq[oi][r] = qkv_bs[o * 16 + lg * 4 + r];
    }
#pragma unroll
    for (int ii = 0; ii < 7; ++ii) {
      s8v xf[4];
#pragma unroll
      for (int kc = 0; kc < 4; ++kc) xf[kc] = ldx(ii, kc);
      f4v qs0 = fzero, qs1 = fzero;
#pragma unroll
      for (int kc = 0; kc < 4; ++kc) {
        qs0 = __builtin_amdgcn_mfma_f32_16x16x32_bf16(wq[0][kc], xf[kc], qs0, 0, 0, 0);
        qs1 = __builtin_amdgcn_mfma_f32_16x16x32_bf16(wq[1][kc], xf[kc], qs1, 0, 0, 0);
      }
#pragma unroll
      for (int r = 0; r < 4; ++r) { qs0[r] += bq[0][r]; qs1[r] += bq[1][r]; }
      float vals[8];
#pragma unroll
      for (int jj = 0; jj < 8; ++jj) {
        int srcLane = l16 + 16 * ((lg & 1) * 2 + (jj >> 2));
        float a = __shfl(qs0[jj & 3], srcLane);
        float c = __shfl(qs1[jj & 3], srcLane);
        vals[jj] = (lg & 2) ? c : a;
      }
      union { s8v v; unsigned u[4]; } tt;
      tt.u[0] = pack2(vals[0], vals[1]); tt.u[1] = pack2(vals[2], vals[3]);
      tt.u[2] = pack2(vals[4], vals[5]); tt.u[3] = pack2(vals[6], vals[7]);
      qfrag[ii] = tt.v;
    }
  }

  // ---- QKV v: normal MFMA -> in-register B-frags via shfl; one oi at a time ----
  s8v vfrag[2][4];
#pragma unroll
  for (int oi = 0; oi < 2; ++oi) {
    s8v wvv[4];
    int o = 16 + 2 * h + oi;
#pragma unroll
    for (int kc = 0; kc < 4; ++kc)
      wvv[kc] = *reinterpret_cast<const s8v*>(&qkv_wb[(o * 16 + l16) * DIMC + kc * 32 + lg * 8]);
    float bv = qkv_bs[256 + h * 32 + oi * 16 + l16];
#pragma unroll
    for (int mtp = 0; mtp < 4; ++mtp) {
      f4v accA = fzero, accB = fzero;
      {
        s8v xf[4];
#pragma unroll
        for (int kc = 0; kc < 4; ++kc) xf[kc] = ldx(2 * mtp, kc);
#pragma unroll
        for (int kc = 0; kc < 4; ++kc)
          accA = __builtin_amdgcn_mfma_f32_16x16x32_bf16(xf[kc], wvv[kc], accA, 0, 0, 0);
#pragma unroll
        for (int r = 0; r < 4; ++r) accA[r] += bv;
      }
      if (mtp < 3) {  // mt=7 absent; v tokens 112..127 stay exactly 0
        s8v xf[4];
#pragma unroll
        for (int kc = 0; kc < 4; ++kc) xf[kc] = ldx(2 * mtp + 1, kc);
#pragma unroll
        for (int kc = 0; kc < 4; ++kc)
          accB = __builtin_amdgcn_mfma_f32_16x16x32_bf16(xf[kc], wvv[kc], accB, 0, 0, 0);
#pragma unroll
        for (int r = 0; r < 4; ++r) accB[r] += bv;
      }
      float vals[8];
#pragma unroll
      for (int jj = 0; jj < 8; ++jj) {
        int srcLane = l16 + 16 * ((lg & 1) * 2 + (jj >> 2));
        float a = __shfl(accA[jj & 3], srcLane);
        float c = __shfl(accB[jj & 3], srcLane);
        vals[jj] = (lg & 2) ? c : a;   // lg>>1 picks mt parity
      }
      union { s8v v; unsigned u[4]; } tt;
      tt.u[0] = pack2(vals[0], vals[1]); tt.u[1] = pack2(vals[2], vals[3]);
      tt.u[2] = pack2(vals[4], vals[5]); tt.u[3] = pack2(vals[6], vals[7]);
      vfrag[oi][mtp] = tt.v;
    }
  }

  // ---- QKV k -> LDS frag-major; one ko (16-chan tile) at a time ----
#pragma unroll
  for (int ko = 0; ko < 2; ++ko) {
    s8v wk[4];
    int o = 8 + 2 * h + ko;
#pragma unroll
    for (int kc = 0; kc < 4; ++kc)
      wk[kc] = *reinterpret_cast<const s8v*>(&qkv_wb[(o * 16 + l16) * DIMC + kc * 32 + lg * 8]);
    float bk = qkv_bs[128 + (2 * h + ko) * 16 + l16];
    // producer lane holds (token=mt*16+lg*4+r, chan=ko*16+l16); frag dest byte:
    // mt*1024 + (lg*4+r)*16 + (ko*2+(l16>>3))*256 + (l16&7)*2
    char* kw = kfb + (ko * 2 + (l16 >> 3)) * 256 + (l16 & 7) * 2 + (lg * 4) * 16;
#pragma unroll
    for (int mt = 0; mt < 7; ++mt) {
      f4v acc = fzero;
#pragma unroll
      for (int kc = 0; kc < 4; ++kc)
        acc = __builtin_amdgcn_mfma_f32_16x16x32_bf16(ldx(mt, kc), wk[kc], acc, 0, 0, 0);
#pragma unroll
      for (int r = 0; r < 4; ++r)
        *reinterpret_cast<ushort*>(kw + mt * 1024 + r * 16) = f2bf(acc[r] + bk);
    }
  }
  __syncthreads();  // QKV done: x dead (ao writable), k frags ready

  // ---- attention (TRANSPOSED): lane l16 = q-row i; regs span k-cols ----
  const float* bmt = bm_g + (size_t)(((b & 63) * 4 + h) * 49) * 256;
  const int bmoff = l16 * 16 + lg * 4;
  float* outb = out + (size_t)b * NTOK * DIMC;
#pragma unroll
  for (int ii = 0; ii < 7; ++ii) {
    f4v S[7];
#pragma unroll
    for (int jt = 0; jt < 7; ++jt) {
      s8v kf = *reinterpret_cast<const s8v*>(kfb + jt * 1024 + lane * 16);
      S[jt] = __builtin_amdgcn_mfma_f32_16x16x32_bf16(kf, qfrag[ii], fzero, 0, 0, 0);
    }
#pragma unroll
    for (int jt = 0; jt < 7; ++jt) {
      f4v bmv = *reinterpret_cast<const f4v*>(&bmt[(ii * 7 + jt) * 256 + bmoff]);
      S[jt] = S[jt] + bmv;
    }
    // lane-local softmax over 28 values + 2-lane-hop reduce (lanes l16+{0,16,32,48})
    float m = fmaxf(fmaxf(S[0][0], S[0][1]), fmaxf(S[0][2], S[0][3]));
#pragma unroll
    for (int jt = 1; jt < 7; ++jt)
      m = fmaxf(m, fmaxf(fmaxf(S[jt][0], S[jt][1]), fmaxf(S[jt][2], S[jt][3])));
    m = fmaxf(m, __shfl_xor(m, 16));
    m = fmaxf(m, __shfl_xor(m, 32));
    float s = 0.f;
#pragma unroll
    for (int jt = 0; jt < 7; ++jt)
#pragma unroll
      for (int r = 0; r < 4; ++r) {
        float p = exp2f(S[jt][r] - m);
        S[jt][r] = p;
        s += p;
      }
    s += __shfl_xor(s, 16);
    s += __shfl_xor(s, 32);
    float inv = 1.0f / s;           // valid for this lane's row i = ii*16 + l16
    // pack p -> bf16 pairs in-lane (adjacent j)
    unsigned pk[7][2];
#pragma unroll
    for (int jt = 0; jt < 7; ++jt) {
      pk[jt][0] = pack2(S[jt][0], S[jt][1]);
      pk[jt][1] = pack2(S[jt][2], S[jt][3]);
    }
    // PV: build A-frags via shfl (same transform as q; valid because register index
    // (w&1) is compile-time in the transposed layout). kc=3 c-side: j 112..127 -> v=0,
    // pa may be junk-but-finite (reuse a).
    f4v o0 = fzero, o1 = fzero;
#pragma unroll
    for (int kc = 0; kc < 4; ++kc) {
      union { s8v v; unsigned u[4]; } pa;
#pragma unroll
      for (int w = 0; w < 4; ++w) {
        int sL = l16 + 16 * ((lg & 1) * 2 + (w >> 1));
        unsigned a = __shfl(pk[2 * kc][w & 1], sL);
        unsigned c = (kc < 3) ? __shfl(pk[2 * kc + 1][w & 1], sL) : a;
        pa.u[w] = (lg & 2) ? c : a;
      }
      o0 = __builtin_amdgcn_mfma_f32_16x16x32_bf16(pa.v, vfrag[0][kc], o0, 0, 0, 0);
      o1 = __builtin_amdgcn_mfma_f32_16x16x32_bf16(pa.v, vfrag[1][kc], o1, 0, 0, 0);
    }
    // normalize (inv fetched from the lane owning row lg*4+r) + immediate ao write
#pragma unroll
    for (int r = 0; r < 4; ++r) {
      float iv = __shfl(inv, lg * 4 + r);
      int n = ii * 16 + lg * 4 + r;
      if (n < NTOK) {
        int c0 = h * 32 + l16;
        *reinterpret_cast<ushort*>(aoc + ((n * 256 + c0 * 2) ^ ((n & 7) << 4))) = f2bf(o0[r] * iv);
        int c1 = c0 + 16;
        *reinterpret_cast<ushort*>(aoc + ((n * 256 + c1 * 2) ^ ((n & 7) << 4))) = f2bf(o1[r] * iv);
      }
    }
  }
  __syncthreads();  // all ao columns written -> proj may read

  // ---- proj: wave h owns row-tiles {h, h+4}; rows 98-111 never read/written ----
#pragma unroll
  for (int pass = 0; pass < 2; ++pass) {
    int rt = h + pass * 4;
    if (rt < 7) {
      const int row = rt * 16 + l16;
#pragma unroll
      for (int ot = 0; ot < 8; ++ot) {
        s8v pw[4];
#pragma unroll
        for (int kc = 0; kc < 4; ++kc)
          pw[kc] = *reinterpret_cast<const s8v*>(&proj_wb[(ot * 16 + l16) * DIMC + kc * 32 + lg * 8]);
        float pb = proj_b[ot * 16 + l16];
        f4v acc = fzero;
#pragma unroll
        for (int kc = 0; kc < 4; ++kc) {
          int off = (row * 256 + kc * 64 + lg * 16) ^ ((row & 7) << 4);
          s8v af = *reinterpret_cast<const s8v*>(aoc + off);
          acc = __builtin_amdgcn_mfma_f32_16x16x32_bf16(af, pw[kc], acc, 0, 0, 0);
        }
#pragma unroll
        for (int r = 0; r < 4; ++r) {
          int n = rt * 16 + lg * 4 + r;
          if (n < NTOK) outb[n * DIMC + ot * 16 + l16] = acc[r] + pb;
        }
      }
    }
  }
}

extern "C" void kernel_launch(void* const* d_in, const int* in_sizes, int n_in,
                              void* d_out, int out_size, void* d_ws, size_t ws_size,
                              hipStream_t stream) {
  const float* x = (const float*)d_in[0];
  const float* mask = (const float*)d_in[1];
  const float* rpb = (const float*)d_in[2];
  const float* qkv_w = (const float*)d_in[3];
  const float* qkv_b = (const float*)d_in[4];
  const float* proj_w = (const float*)d_in[5];
  const float* proj_b = (const float*)d_in[6];
  const int* rel_idx = (const int*)d_in[7];

  char* ws = (char*)d_ws;
  float* bm = (float*)ws;                                   // 64*4*49*1024 = 12,845,056 B
  ushort* qkv_wb = (ushort*)(ws + 12845056);                // 384*128*2    =     98,304 B
  float* qkv_bs = (float*)(ws + 12845056 + 98304);          // 384*4        =      1,536 B
  ushort* proj_wb = (ushort*)(ws + 12845056 + 98304 + 1536);// 128*128*2    =     32,768 B

  setup_kernel<<<dim3(1024), dim3(256), 0, stream>>>(rpb, rel_idx, mask, qkv_w, qkv_b,
                                                     proj_w, bm, qkv_wb, qkv_bs, proj_wb);
  fused_wattn<<<dim3(4096), dim3(256), 0, stream>>>(x, bm, qkv_bs, qkv_wb, proj_wb,
                                                    proj_b, (float*)d_out);
}

// Round 8
// 362.292 us; speedup vs baseline: 3.2439x; 1.2156x over previous
//
#include <hip/hip_runtime.h>

#define NTOK 98
#define DIMC 128

typedef __attribute__((ext_vector_type(8))) short s8v;
typedef __attribute__((ext_vector_type(4))) float f4v;

#define LOG2E 1.4426950408889634f
#define QSCALE (0.17677669529663687f * LOG2E)  // 32^-0.5 * log2(e), folded into Wq/bq

__device__ __forceinline__ ushort f2bf(float f) {
  union { float fv; unsigned u; } c; c.fv = f;
  unsigned r = c.u + 0x7fffu + ((c.u >> 16) & 1u);
  return (ushort)(r >> 16);
}
__device__ __forceinline__ unsigned pack2(float a, float b) {
  return (unsigned)f2bf(a) | ((unsigned)f2bf(b) << 16);
}

// bm tiled+padded, TRANSPOSED mapping (matches S_T = K@Q^T C-layout):
// element at tile(it,jt)*256 + l16*16 + lg*4 + r  is for  i = it*16 + l16 (q row),
// j = jt*16 + lg*4 + r (k col); -1e30 baked for i>=98 or j>=98.
__global__ void setup_kernel(const float* __restrict__ rpb, const int* __restrict__ rel_idx,
                             const float* __restrict__ maskg,
                             const float* __restrict__ qkv_w, const float* __restrict__ qkv_b,
                             const float* __restrict__ proj_w,
                             float* __restrict__ bm, ushort* __restrict__ qkv_wb,
                             float* __restrict__ qkv_bs, ushort* __restrict__ proj_wb) {
  int tid = blockIdx.x * blockDim.x + threadIdx.x;
  int stride = gridDim.x * blockDim.x;
  const int NN = NTOK * NTOK;
  for (int idx = tid; idx < 64 * 4 * 49 * 256; idx += stride) {
    int wh = idx / (49 * 256);
    int rest = idx % (49 * 256);
    int tile = rest >> 8;
    int e = rest & 255;
    int it = tile / 7, jt = tile % 7;
    int l16 = e >> 4, lg = (e >> 2) & 3, r = e & 3;
    int i = it * 16 + l16;            // TRANSPOSED: i from l16
    int j = jt * 16 + lg * 4 + r;     //             j from (lg, r)
    int w = wh >> 2, h = wh & 3;
    float v = -1e30f;
    if (i < NTOK && j < NTOK)
      v = (maskg[w * NN + i * NTOK + j] + rpb[rel_idx[i * NTOK + j] * 4 + h]) * LOG2E;
    bm[idx] = v;
  }
  for (int idx = tid; idx < 384 * DIMC; idx += stride) {
    float s = (idx < DIMC * DIMC) ? QSCALE : 1.0f;
    qkv_wb[idx] = f2bf(qkv_w[idx] * s);
  }
  for (int idx = tid; idx < 384; idx += stride)
    qkv_bs[idx] = qkv_b[idx] * ((idx < DIMC) ? QSCALE : 1.0f);
  for (int idx = tid; idx < DIMC * DIMC; idx += stride) proj_wb[idx] = f2bf(proj_w[idx]);
}

// 256-thread block = ONE window, wave = head (4 waves). LDS 53760 B -> 3 blocks/CU.
//   R1 [0,25088):  x [98][128] bf16 swizzled; progressively overwritten by ao rows
//                  DURING attention (itile ii: x rows [16ii,16ii+16) die at q-build(ii),
//                  ao rows [16ii,16ii+16) written at iteration end; per-itile
//                  __syncthreads() between q-build and the rest makes this race-free).
//   R2 [25088,53760): k frag-major [head 4][jt 7][lane 64][16 B]; ds_read_b128 conflict-free.
// r8 change vs r7: qfrag[7] (28 persistent regs) deleted — q built per-itile from x in LDS
// (wq kept persistent). The per-itile barrier is also a full memory fence -> compiler can't
// hoist next-itile bm/LDS loads (r7's live-range explosion -> 440 MB scratch spill traffic).
// Register/occupancy empirics: waves_per_eu(3) caps TOTAL (arch+acc) regs ~170 (512-reg
// pool / 3); r7 demand ~200 spilled (WRITE 538 MB vs 205 ideal). This structure ~150.
__global__ __launch_bounds__(256) __attribute__((amdgpu_waves_per_eu(3)))
void fused_wattn(const float* __restrict__ x, const float* __restrict__ bm_g,
                 const float* __restrict__ qkv_bs,
                 const ushort* __restrict__ qkv_wb, const ushort* __restrict__ proj_wb,
                 const float* __restrict__ proj_b, float* __restrict__ out) {
  __shared__ ushort smem[26880];
  const int b = blockIdx.x;
  const int tid = threadIdx.x;
  const int h = tid >> 6;      // wave index == head
  const int lane = tid & 63;
  const int l16 = lane & 15;
  const int lg = lane >> 4;

  char* xc = reinterpret_cast<char*>(smem);
  char* aoc = reinterpret_cast<char*>(smem);
  char* kfb = reinterpret_cast<char*>(smem) + 25088 + h * 7168;  // this head's k frags

  // ---- stage x -> bf16 LDS (swizzled), rows 0..97 only ----
  {
    const float4* x4 = reinterpret_cast<const float4*>(x + (size_t)b * NTOK * DIMC);
    for (int i = tid; i < 3136; i += 256) {
      float4 f = x4[i];
      uint2 u; u.x = pack2(f.x, f.y); u.y = pack2(f.z, f.w);
      int row = i >> 5;
      *reinterpret_cast<uint2*>(xc + ((i * 8) ^ ((row & 7) << 4))) = u;
    }
  }
  __syncthreads();

  // mt==6, l16>=2 reads rows 98..111 -> junk LDS (k region); force 0 in registers
  // (possibly-Inf/NaN junk caused r5's failure).
  auto ldx = [&](int mt, int kc) -> s8v {
    int row = mt * 16 + l16;
    int off = (row * 256 + kc * 64 + lg * 16) ^ ((row & 7) << 4);
    s8v v = *reinterpret_cast<const s8v*>(xc + off);
    if (mt == 6 && l16 >= 2) {
      s8v z = {0, 0, 0, 0, 0, 0, 0, 0};
      v = z;
    }
    return v;
  };

  const f4v fzero = {0.f, 0.f, 0.f, 0.f};

  // ---- persistent q weights (live through attention; q built per-itile) ----
  s8v wq[2][4];
  float bq[2][4];
#pragma unroll
  for (int oi = 0; oi < 2; ++oi) {
    int o = 2 * h + oi;
#pragma unroll
    for (int kc = 0; kc < 4; ++kc)
      wq[oi][kc] = *reinterpret_cast<const s8v*>(&qkv_wb[(o * 16 + l16) * DIMC + kc * 32 + lg * 8]);
#pragma unroll
    for (int r = 0; r < 4; ++r) bq[oi][r] = qkv_bs[o * 16 + lg * 4 + r];
  }

  // ---- QKV v: normal MFMA -> in-register B-frags via shfl; one oi at a time ----
  s8v vfrag[2][4];
#pragma unroll
  for (int oi = 0; oi < 2; ++oi) {
    s8v wvv[4];
    int o = 16 + 2 * h + oi;
#pragma unroll
    for (int kc = 0; kc < 4; ++kc)
      wvv[kc] = *reinterpret_cast<const s8v*>(&qkv_wb[(o * 16 + l16) * DIMC + kc * 32 + lg * 8]);
    float bv = qkv_bs[256 + h * 32 + oi * 16 + l16];
#pragma unroll
    for (int mtp = 0; mtp < 4; ++mtp) {
      f4v accA = fzero, accB = fzero;
      {
        s8v xf[4];
#pragma unroll
        for (int kc = 0; kc < 4; ++kc) xf[kc] = ldx(2 * mtp, kc);
#pragma unroll
        for (int kc = 0; kc < 4; ++kc)
          accA = __builtin_amdgcn_mfma_f32_16x16x32_bf16(xf[kc], wvv[kc], accA, 0, 0, 0);
#pragma unroll
        for (int r = 0; r < 4; ++r) accA[r] += bv;
      }
      if (mtp < 3) {  // mt=7 absent; v tokens 112..127 stay exactly 0
        s8v xf[4];
#pragma unroll
        for (int kc = 0; kc < 4; ++kc) xf[kc] = ldx(2 * mtp + 1, kc);
#pragma unroll
        for (int kc = 0; kc < 4; ++kc)
          accB = __builtin_amdgcn_mfma_f32_16x16x32_bf16(xf[kc], wvv[kc], accB, 0, 0, 0);
#pragma unroll
        for (int r = 0; r < 4; ++r) accB[r] += bv;
      }
      float vals[8];
#pragma unroll
      for (int jj = 0; jj < 8; ++jj) {
        int srcLane = l16 + 16 * ((lg & 1) * 2 + (jj >> 2));
        float a = __shfl(accA[jj & 3], srcLane);
        float c = __shfl(accB[jj & 3], srcLane);
        vals[jj] = (lg & 2) ? c : a;   // lg>>1 picks mt parity
      }
      union { s8v v; unsigned u[4]; } tt;
      tt.u[0] = pack2(vals[0], vals[1]); tt.u[1] = pack2(vals[2], vals[3]);
      tt.u[2] = pack2(vals[4], vals[5]); tt.u[3] = pack2(vals[6], vals[7]);
      vfrag[oi][mtp] = tt.v;
    }
  }

  // ---- QKV k -> LDS frag-major; one ko (16-chan tile) at a time ----
#pragma unroll
  for (int ko = 0; ko < 2; ++ko) {
    s8v wk[4];
    int o = 8 + 2 * h + ko;
#pragma unroll
    for (int kc = 0; kc < 4; ++kc)
      wk[kc] = *reinterpret_cast<const s8v*>(&qkv_wb[(o * 16 + l16) * DIMC + kc * 32 + lg * 8]);
    float bk = qkv_bs[128 + (2 * h + ko) * 16 + l16];
    // producer lane holds (token=mt*16+lg*4+r, chan=ko*16+l16); frag dest byte:
    // mt*1024 + (lg*4+r)*16 + (ko*2+(l16>>3))*256 + (l16&7)*2
    char* kw = kfb + (ko * 2 + (l16 >> 3)) * 256 + (l16 & 7) * 2 + (lg * 4) * 16;
#pragma unroll
    for (int mt = 0; mt < 7; ++mt) {
      f4v acc = fzero;
#pragma unroll
      for (int kc = 0; kc < 4; ++kc)
        acc = __builtin_amdgcn_mfma_f32_16x16x32_bf16(ldx(mt, kc), wk[kc], acc, 0, 0, 0);
#pragma unroll
      for (int r = 0; r < 4; ++r)
        *reinterpret_cast<ushort*>(kw + mt * 1024 + r * 16) = f2bf(acc[r] + bk);
    }
  }
  __syncthreads();  // k frags ready; v,k done with x (q still needs it, per-itile)

  // ---- attention (TRANSPOSED): lane l16 = q-row i; regs span k-cols ----
  const float* bmt = bm_g + (size_t)(((b & 63) * 4 + h) * 49) * 256;
  const int bmoff = l16 * 16 + lg * 4;
  float* outb = out + (size_t)b * NTOK * DIMC;
#pragma unroll
  for (int ii = 0; ii < 7; ++ii) {
    // -- q-build for itile ii (consumes x rows [16ii,16ii+16)) --
    s8v qfrag;
    {
      s8v xf[4];
#pragma unroll
      for (int kc = 0; kc < 4; ++kc) xf[kc] = ldx(ii, kc);
      f4v qs0 = fzero, qs1 = fzero;
#pragma unroll
      for (int kc = 0; kc < 4; ++kc) {
        qs0 = __builtin_amdgcn_mfma_f32_16x16x32_bf16(wq[0][kc], xf[kc], qs0, 0, 0, 0);
        qs1 = __builtin_amdgcn_mfma_f32_16x16x32_bf16(wq[1][kc], xf[kc], qs1, 0, 0, 0);
      }
#pragma unroll
      for (int r = 0; r < 4; ++r) { qs0[r] += bq[0][r]; qs1[r] += bq[1][r]; }
      float vals[8];
#pragma unroll
      for (int jj = 0; jj < 8; ++jj) {
        int srcLane = l16 + 16 * ((lg & 1) * 2 + (jj >> 2));
        float a = __shfl(qs0[jj & 3], srcLane);
        float c = __shfl(qs1[jj & 3], srcLane);
        vals[jj] = (lg & 2) ? c : a;
      }
      union { s8v v; unsigned u[4]; } tt;
      tt.u[0] = pack2(vals[0], vals[1]); tt.u[1] = pack2(vals[2], vals[3]);
      tt.u[2] = pack2(vals[4], vals[5]); tt.u[3] = pack2(vals[6], vals[7]);
      qfrag = tt.v;
    }
    // All waves have consumed x[ii]; after this barrier ao[ii] writes are safe.
    // (Also a full memory fence: stops cross-itile load hoisting -> bounded live range.)
    __syncthreads();

    f4v S[7];
#pragma unroll
    for (int jt = 0; jt < 7; ++jt) {
      s8v kf = *reinterpret_cast<const s8v*>(kfb + jt * 1024 + lane * 16);
      S[jt] = __builtin_amdgcn_mfma_f32_16x16x32_bf16(kf, qfrag, fzero, 0, 0, 0);
    }
#pragma unroll
    for (int jt = 0; jt < 7; ++jt) {
      f4v bmv = *reinterpret_cast<const f4v*>(&bmt[(ii * 7 + jt) * 256 + bmoff]);
      S[jt] = S[jt] + bmv;
    }
    // lane-local softmax over 28 values + 2-lane-hop reduce (lanes l16+{0,16,32,48})
    float m = fmaxf(fmaxf(S[0][0], S[0][1]), fmaxf(S[0][2], S[0][3]));
#pragma unroll
    for (int jt = 1; jt < 7; ++jt)
      m = fmaxf(m, fmaxf(fmaxf(S[jt][0], S[jt][1]), fmaxf(S[jt][2], S[jt][3])));
    m = fmaxf(m, __shfl_xor(m, 16));
    m = fmaxf(m, __shfl_xor(m, 32));
    float s = 0.f;
#pragma unroll
    for (int jt = 0; jt < 7; ++jt)
#pragma unroll
      for (int r = 0; r < 4; ++r) {
        float p = exp2f(S[jt][r] - m);
        S[jt][r] = p;
        s += p;
      }
    s += __shfl_xor(s, 16);
    s += __shfl_xor(s, 32);
    float inv = 1.0f / s;           // valid for this lane's row i = ii*16 + l16
    // pack p -> bf16 pairs in-lane (adjacent j)
    unsigned pk[7][2];
#pragma unroll
    for (int jt = 0; jt < 7; ++jt) {
      pk[jt][0] = pack2(S[jt][0], S[jt][1]);
      pk[jt][1] = pack2(S[jt][2], S[jt][3]);
    }
    // PV: build A-frags via shfl (register index compile-time in transposed layout).
    // kc=3 c-side: j 112..127 -> v=0, pa junk-but-finite (reuse a).
    f4v o0 = fzero, o1 = fzero;
#pragma unroll
    for (int kc = 0; kc < 4; ++kc) {
      union { s8v v; unsigned u[4]; } pa;
#pragma unroll
      for (int w = 0; w < 4; ++w) {
        int sL = l16 + 16 * ((lg & 1) * 2 + (w >> 1));
        unsigned a = __shfl(pk[2 * kc][w & 1], sL);
        unsigned c = (kc < 3) ? __shfl(pk[2 * kc + 1][w & 1], sL) : a;
        pa.u[w] = (lg & 2) ? c : a;
      }
      o0 = __builtin_amdgcn_mfma_f32_16x16x32_bf16(pa.v, vfrag[0][kc], o0, 0, 0, 0);
      o1 = __builtin_amdgcn_mfma_f32_16x16x32_bf16(pa.v, vfrag[1][kc], o1, 0, 0, 0);
    }
    // normalize (inv fetched from the lane owning row lg*4+r) + immediate ao write
#pragma unroll
    for (int r = 0; r < 4; ++r) {
      float iv = __shfl(inv, lg * 4 + r);
      int n = ii * 16 + lg * 4 + r;
      if (n < NTOK) {
        int c0 = h * 32 + l16;
        *reinterpret_cast<ushort*>(aoc + ((n * 256 + c0 * 2) ^ ((n & 7) << 4))) = f2bf(o0[r] * iv);
        int c1 = c0 + 16;
        *reinterpret_cast<ushort*>(aoc + ((n * 256 + c1 * 2) ^ ((n & 7) << 4))) = f2bf(o1[r] * iv);
      }
    }
  }
  __syncthreads();  // all ao columns written -> proj may read

  // ---- proj: wave h owns row-tiles {h, h+4}; rt=6 reads rows 98-111 = dead k-frag
  // region (finite bf16) -> junk only in write-guarded rows ----
#pragma unroll
  for (int pass = 0; pass < 2; ++pass) {
    int rt = h + pass * 4;
    if (rt < 7) {
      const int row = rt * 16 + l16;
#pragma unroll
      for (int ot = 0; ot < 8; ++ot) {
        s8v pw[4];
#pragma unroll
        for (int kc = 0; kc < 4; ++kc)
          pw[kc] = *reinterpret_cast<const s8v*>(&proj_wb[(ot * 16 + l16) * DIMC + kc * 32 + lg * 8]);
        float pb = proj_b[ot * 16 + l16];
        f4v acc = fzero;
#pragma unroll
        for (int kc = 0; kc < 4; ++kc) {
          int off = (row * 256 + kc * 64 + lg * 16) ^ ((row & 7) << 4);
          s8v af = *reinterpret_cast<const s8v*>(aoc + off);
          acc = __builtin_amdgcn_mfma_f32_16x16x32_bf16(af, pw[kc], acc, 0, 0, 0);
        }
#pragma unroll
        for (int r = 0; r < 4; ++r) {
          int n = rt * 16 + lg * 4 + r;
          if (n < NTOK) outb[n * DIMC + ot * 16 + l16] = acc[r] + pb;
        }
      }
    }
  }
}

extern "C" void kernel_launch(void* const* d_in, const int* in_sizes, int n_in,
                              void* d_out, int out_size, void* d_ws, size_t ws_size,
                              hipStream_t stream) {
  const float* x = (const float*)d_in[0];
  const float* mask = (const float*)d_in[1];
  const float* rpb = (const float*)d_in[2];
  const float* qkv_w = (const float*)d_in[3];
  const float* qkv_b = (const float*)d_in[4];
  const float* proj_w = (const float*)d_in[5];
  const float* proj_b = (const float*)d_in[6];
  const int* rel_idx = (const int*)d_in[7];

  char* ws = (char*)d_ws;
  float* bm = (float*)ws;                                   // 64*4*49*1024 = 12,845,056 B
  ushort* qkv_wb = (ushort*)(ws + 12845056);                // 384*128*2    =     98,304 B
  float* qkv_bs = (float*)(ws + 12845056 + 98304);          // 384*4        =      1,536 B
  ushort* proj_wb = (ushort*)(ws + 12845056 + 98304 + 1536);// 128*128*2    =     32,768 B

  setup_kernel<<<dim3(1024), dim3(256), 0, stream>>>(rpb, rel_idx, mask, qkv_w, qkv_b,
                                                     proj_w, bm, qkv_wb, qkv_bs, proj_wb);
  fused_wattn<<<dim3(4096), dim3(256), 0, stream>>>(x, bm, qkv_bs, qkv_wb, proj_wb,
                                                    proj_b, (float*)d_out);
}